// Round 1
// baseline (572.513 us; speedup 1.0000x reference)
//
#include <hip/hip_runtime.h>
#include <hip/hip_bf16.h>

#define B_ 2
#define T_ 2048
#define C_ 2048
#define H_ 16
#define KH_ 4
#define D_ 128

typedef unsigned short ushort_t;
typedef __attribute__((ext_vector_type(8))) short short8;
typedef __attribute__((ext_vector_type(4))) float f32x4;

#define RSQRT_D 0.08838834764831845f
#define L2E 1.4426950408889634f

__device__ __forceinline__ ushort_t f2b(float f) {
  union { float f; unsigned u; } v; v.f = f;
  unsigned r = v.u + 0x7fffu + ((v.u >> 16) & 1u);
  return (ushort_t)(r >> 16);
}
__device__ __forceinline__ float b2f(ushort_t u) {
  union { unsigned u; float f; } v; v.u = ((unsigned)u) << 16;
  return v.f;
}

__device__ __forceinline__ f32x4 mfma16(short8 a, short8 b, f32x4 c) {
  return __builtin_amdgcn_mfma_f32_16x16x32_bf16(a, b, c, 0, 0, 0);
}

__device__ __forceinline__ void async16(const void* g, void* l) {
  __builtin_amdgcn_global_load_lds(
      (const __attribute__((address_space(1))) void*)g,
      (__attribute__((address_space(3))) void*)l, 16, 0, 0);
}

// ---------------- small prep kernels ----------------

__global__ void convert_f32_bf16(const float* __restrict__ in, ushort_t* __restrict__ out, int n4) {
  int i = blockIdx.x * blockDim.x + threadIdx.x;
  if (i >= n4) return;
  float4 v = ((const float4*)in)[i];
  ushort4 o;
  o.x = f2b(v.x); o.y = f2b(v.y); o.z = f2b(v.z); o.w = f2b(v.w);
  ((ushort4*)out)[i] = o;
}

// out[c][r] = bf16(in[r][c]);  in: R x C f32, out: C x R bf16
__global__ void transpose_to_bf16(const float* __restrict__ in, ushort_t* __restrict__ out, int R, int C) {
  __shared__ float tile[32][33];
  int c0 = blockIdx.x * 32, r0 = blockIdx.y * 32;
  int tx = threadIdx.x, ty = threadIdx.y;
#pragma unroll
  for (int i = 0; i < 4; i++) {
    int r = ty + i * 8;
    tile[r][tx] = in[(size_t)(r0 + r) * C + c0 + tx];
  }
  __syncthreads();
#pragma unroll
  for (int i = 0; i < 4; i++) {
    int r = ty + i * 8;
    out[(size_t)(c0 + r) * R + r0 + tx] = f2b(tile[tx][r]);
  }
}

// cos/sin table: tab[t*64+d] = (cos(t*omega[d]), sin(t*omega[d]))
__global__ void rope_tab_k(const float* __restrict__ omega, float2* __restrict__ tab) {
  int idx = blockIdx.x * blockDim.x + threadIdx.x;  // 2048*64
  int d = idx & 63;
  int t = idx >> 6;
  float ang = (float)t * omega[d];
  tab[idx] = make_float2(cosf(ang), sinf(ang));
}

// Qraw [b*T+t][h*128+d] -> rope -> Qb [(b*16+h)*T + t][d]
__global__ void rope_q_k(const ushort_t* __restrict__ Qraw, const float2* __restrict__ tab,
                         ushort_t* __restrict__ Qb) {
  int idx = blockIdx.x * blockDim.x + threadIdx.x;  // B*T*H*64 = 4194304
  int d = idx & 63;
  int h = (idx >> 6) & 15;
  int t = (idx >> 10) & 2047;
  int b = idx >> 21;
  size_t in_off = ((size_t)(b * 2048 + t) * 16 + h) * 128 + d;
  float x1 = b2f(Qraw[in_off]);
  float x2 = b2f(Qraw[in_off + 64]);
  float2 cs = tab[t * 64 + d];
  size_t out_off = ((size_t)(b * 16 + h) * 2048 + t) * 128 + d;
  Qb[out_off] = f2b(x1 * cs.x - x2 * cs.y);
  Qb[out_off + 64] = f2b(x1 * cs.y + x2 * cs.x);
}

// KVraw cols 0..511 = k -> rope -> Kb [(b*4+kh)*T + t][d]
__global__ void rope_k_k(const ushort_t* __restrict__ KVraw, const float2* __restrict__ tab,
                         ushort_t* __restrict__ Kb) {
  int idx = blockIdx.x * blockDim.x + threadIdx.x;  // B*T*KH*64 = 1048576
  int d = idx & 63;
  int kh = (idx >> 6) & 3;
  int t = (idx >> 8) & 2047;
  int b = idx >> 19;
  size_t in_off = (size_t)(b * 2048 + t) * 1024 + kh * 128 + d;
  float x1 = b2f(KVraw[in_off]);
  float x2 = b2f(KVraw[in_off + 64]);
  float2 cs = tab[t * 64 + d];
  size_t out_off = ((size_t)(b * 4 + kh) * 2048 + t) * 128 + d;
  Kb[out_off] = f2b(x1 * cs.x - x2 * cs.y);
  Kb[out_off + 64] = f2b(x1 * cs.y + x2 * cs.x);
}

// V transpose: KVraw cols 512..1023 -> Vt [(b*4+kh)*128 + d][t]
__global__ void v_trans_k(const ushort_t* __restrict__ KVraw, ushort_t* __restrict__ Vt) {
  __shared__ ushort_t tile[32][33];
  int z = blockIdx.z;        // b*4+kh
  int b = z >> 2, kh = z & 3;
  int d0 = blockIdx.y * 32;
  int t0 = blockIdx.x * 32;
  int tx = threadIdx.x, ty = threadIdx.y;
#pragma unroll
  for (int i = 0; i < 4; i++) {
    int tt = ty + i * 8;
    tile[tt][tx] = KVraw[(size_t)(b * 2048 + t0 + tt) * 1024 + 512 + kh * 128 + d0 + tx];
  }
  __syncthreads();
#pragma unroll
  for (int i = 0; i < 4; i++) {
    int dd = ty + i * 8;
    Vt[((size_t)z * 128 + d0 + dd) * 2048 + t0 + tx] = tile[tx][dd];
  }
}

// ---------------- GEMM: C[M][N] = A[M][K] @ Bt[N][K]^T  (bf16 in, f32 acc) ----------------

__device__ __forceinline__ void store_out(float* C, size_t idx, float v) { C[idx] = v; }
__device__ __forceinline__ void store_out(ushort_t* C, size_t idx, float v) { C[idx] = f2b(v); }

template <typename OUT_T>
__global__ __launch_bounds__(256) void gemm_bt(const ushort_t* __restrict__ A,
                                               const ushort_t* __restrict__ Bt,
                                               OUT_T* __restrict__ C,
                                               int M, int N, int K) {
  __shared__ __attribute__((aligned(16))) ushort_t As[128 * 32];
  __shared__ __attribute__((aligned(16))) ushort_t Bs[128 * 32];
  const int tid = threadIdx.x;
  const int lane = tid & 63;
  const int w = tid >> 6;
  const int bm = blockIdx.y, bn = blockIdx.x;
  const int lr = lane & 15, lc = lane >> 4;
  const int wr = (w >> 1) * 64, wc = (w & 1) * 64;
  const ushort_t* Ab = A + (size_t)bm * 128 * K;
  const ushort_t* Bb = Bt + (size_t)bn * 128 * K;
  const int srow = tid >> 2;
  const int scol = (tid & 3) * 8;
  f32x4 acc[4][4];
#pragma unroll
  for (int i = 0; i < 4; i++)
#pragma unroll
    for (int j = 0; j < 4; j++) acc[i][j] = (f32x4)(0.0f);

  for (int k0 = 0; k0 < K; k0 += 32) {
    async16(Ab + (size_t)srow * K + k0 + scol, As + srow * 32 + scol);
    async16(Ab + (size_t)(srow + 64) * K + k0 + scol, As + (srow + 64) * 32 + scol);
    async16(Bb + (size_t)srow * K + k0 + scol, Bs + srow * 32 + scol);
    async16(Bb + (size_t)(srow + 64) * K + k0 + scol, Bs + (srow + 64) * 32 + scol);
    __syncthreads();
    short8 af[4], bf[4];
#pragma unroll
    for (int mi = 0; mi < 4; mi++)
      af[mi] = *(const short8*)(As + (wr + mi * 16 + lr) * 32 + lc * 8);
#pragma unroll
    for (int ni = 0; ni < 4; ni++)
      bf[ni] = *(const short8*)(Bs + (wc + ni * 16 + lr) * 32 + lc * 8);
#pragma unroll
    for (int mi = 0; mi < 4; mi++)
#pragma unroll
      for (int ni = 0; ni < 4; ni++)
        acc[mi][ni] = mfma16(af[mi], bf[ni], acc[mi][ni]);
    __syncthreads();
  }
#pragma unroll
  for (int mi = 0; mi < 4; mi++) {
#pragma unroll
    for (int ni = 0; ni < 4; ni++) {
      int row = bm * 128 + wr + mi * 16 + lc * 4;
      int col = bn * 128 + wc + ni * 16 + lr;
#pragma unroll
      for (int r = 0; r < 4; r++)
        store_out(C, (size_t)(row + r) * N + col, acc[mi][ni][r]);
    }
  }
}

// ---------------- flash attention (causal GQA) ----------------
// grid (T/16, H, B), 1 wave per block.
// Qb: [(b*16+h)*T + t][128], Kb: [(b*4+kh)*T + t][128], Vt: [(b*4+kh)*128 + d][T]
// Yb: [b*T + t][h*128 + d]  (bf16)
__global__ __launch_bounds__(64) void attn_k(const ushort_t* __restrict__ Qb,
                                             const ushort_t* __restrict__ Kb,
                                             const ushort_t* __restrict__ Vt,
                                             ushort_t* __restrict__ Yb) {
  __shared__ __attribute__((aligned(16))) ushort_t p_lds[16 * 32];
  const int lane = threadIdx.x;
  const int q0 = blockIdx.x * 16;
  const int h = blockIdx.y;
  const int b = blockIdx.z;
  const int kh = h >> 2;
  const int lr = lane & 15, lc = lane >> 4;

  const ushort_t* Qp = Qb + (size_t)(b * 16 + h) * T_ * D_;
  const ushort_t* Kp = Kb + (size_t)(b * 4 + kh) * T_ * D_;
  const ushort_t* Vp = Vt + (size_t)(b * 4 + kh) * D_ * T_;

  short8 qf[4];
#pragma unroll
  for (int c = 0; c < 4; c++)
    qf[c] = *(const short8*)(Qp + (size_t)(q0 + lr) * D_ + c * 32 + lc * 8);

  f32x4 o[8];
#pragma unroll
  for (int n = 0; n < 8; n++) o[n] = (f32x4)(0.0f);
  float m[4], lsum[4];
#pragma unroll
  for (int r = 0; r < 4; r++) { m[r] = -1e30f; lsum[r] = 0.0f; }

  const int ntiles = (q0 + 47) >> 5;  // kv tiles of 32, kv0 <= q0+15
  for (int ti = 0; ti < ntiles; ti++) {
    int kv0 = ti * 32;
    f32x4 s0 = (f32x4)(0.0f), s1 = (f32x4)(0.0f);
#pragma unroll
    for (int c = 0; c < 4; c++) {
      short8 k0f = *(const short8*)(Kp + (size_t)(kv0 + lr) * D_ + c * 32 + lc * 8);
      short8 k1f = *(const short8*)(Kp + (size_t)(kv0 + 16 + lr) * D_ + c * 32 + lc * 8);
      s0 = mfma16(qf[c], k0f, s0);
      s1 = mfma16(qf[c], k1f, s1);
    }
    // scale + causal mask; S[q][kv]: q = q0+lc*4+r, kv = kv0+lr (+16)
    float p0[4], p1[4], tm[4];
#pragma unroll
    for (int r = 0; r < 4; r++) {
      int q = q0 + lc * 4 + r;
      float a0 = s0[r] * RSQRT_D;
      float a1 = s1[r] * RSQRT_D;
      if (kv0 + lr > q) a0 = -1e30f;
      if (kv0 + 16 + lr > q) a1 = -1e30f;
      p0[r] = a0; p1[r] = a1;
      tm[r] = fmaxf(a0, a1);
    }
#pragma unroll
    for (int off = 1; off < 16; off <<= 1)
#pragma unroll
      for (int r = 0; r < 4; r++) tm[r] = fmaxf(tm[r], __shfl_xor(tm[r], off));
    float al[4];
#pragma unroll
    for (int r = 0; r < 4; r++) {
      float mn = fmaxf(m[r], tm[r]);
      al[r] = exp2f((m[r] - mn) * L2E);
      p0[r] = exp2f((p0[r] - mn) * L2E);
      p1[r] = exp2f((p1[r] - mn) * L2E);
      m[r] = mn;
    }
    float rs[4];
#pragma unroll
    for (int r = 0; r < 4; r++) rs[r] = p0[r] + p1[r];
#pragma unroll
    for (int off = 1; off < 16; off <<= 1)
#pragma unroll
      for (int r = 0; r < 4; r++) rs[r] += __shfl_xor(rs[r], off);
#pragma unroll
    for (int r = 0; r < 4; r++) lsum[r] = lsum[r] * al[r] + rs[r];
#pragma unroll
    for (int n = 0; n < 8; n++)
#pragma unroll
      for (int r = 0; r < 4; r++) o[n][r] *= al[r];

    __syncthreads();  // previous-iteration P reads done before overwrite
#pragma unroll
    for (int r = 0; r < 4; r++) {
      p_lds[(lc * 4 + r) * 32 + lr] = f2b(p0[r]);
      p_lds[(lc * 4 + r) * 32 + lr + 16] = f2b(p1[r]);
    }
    __syncthreads();
    short8 pf = *(const short8*)(p_lds + lr * 32 + lc * 8);
#pragma unroll
    for (int n = 0; n < 8; n++) {
      short8 vf = *(const short8*)(Vp + (size_t)(n * 16 + lr) * T_ + kv0 + lc * 8);
      o[n] = mfma16(pf, vf, o[n]);
    }
  }
  float inv[4];
#pragma unroll
  for (int r = 0; r < 4; r++) inv[r] = 1.0f / lsum[r];
#pragma unroll
  for (int n = 0; n < 8; n++) {
#pragma unroll
    for (int r = 0; r < 4; r++) {
      int q = q0 + lc * 4 + r;
      int d = n * 16 + lr;
      Yb[(size_t)(b * T_ + q) * 2048 + h * 128 + d] = f2b(o[n][r] * inv[r]);
    }
  }
}

// ---------------- launch ----------------

extern "C" void kernel_launch(void* const* d_in, const int* in_sizes, int n_in,
                              void* d_out, int out_size, void* d_ws, size_t ws_size,
                              hipStream_t stream) {
  (void)in_sizes; (void)n_in; (void)out_size; (void)ws_size;
  const float* x = (const float*)d_in[0];
  const float* wq = (const float*)d_in[1];
  const float* wkv = (const float*)d_in[2];
  const float* wproj = (const float*)d_in[3];
  const float* omega = (const float*)d_in[4];
  float* out = (float*)d_out;
  char* ws = (char*)d_ws;

  ushort_t* xb     = (ushort_t*)(ws + 0);          // 4096x2048 bf16 = 16.8MB
  ushort_t* wqT    = (ushort_t*)(ws + 16777216);   // 2048x2048 bf16
  ushort_t* wkvT   = (ushort_t*)(ws + 25165824);   // 1024x2048 bf16
  ushort_t* wprojT = (ushort_t*)(ws + 29360128);   // 2048x2048 bf16
  ushort_t* Qraw   = (ushort_t*)(ws + 37748736);   // 4096x2048 bf16
  ushort_t* KVraw  = (ushort_t*)(ws + 54525952);   // 4096x1024 bf16
  ushort_t* Qb     = (ushort_t*)(ws + 62914560);   // [b][h][t][d] bf16
  ushort_t* Kb     = (ushort_t*)(ws + 79691776);   // [b][kh][t][d] bf16
  ushort_t* Vt     = (ushort_t*)(ws + 83886080);   // [b][kh][d][t] bf16
  ushort_t* Yb     = (ushort_t*)(ws + 88080384);   // 4096x2048 bf16
  float2*   tab    = (float2*)(ws + 104857600);    // 2048x64 float2 = 1MB

  convert_f32_bf16<<<8192, 256, 0, stream>>>(x, xb, 2097152);
  transpose_to_bf16<<<dim3(64, 64), dim3(32, 8), 0, stream>>>(wq, wqT, 2048, 2048);
  transpose_to_bf16<<<dim3(32, 64), dim3(32, 8), 0, stream>>>(wkv, wkvT, 2048, 1024);
  transpose_to_bf16<<<dim3(64, 64), dim3(32, 8), 0, stream>>>(wproj, wprojT, 2048, 2048);
  rope_tab_k<<<512, 256, 0, stream>>>(omega, tab);

  gemm_bt<<<dim3(16, 32), 256, 0, stream>>>(xb, wqT, Qraw, 4096, 2048, 2048);
  gemm_bt<<<dim3(8, 32), 256, 0, stream>>>(xb, wkvT, KVraw, 4096, 1024, 2048);

  rope_q_k<<<16384, 256, 0, stream>>>(Qraw, tab, Qb);
  rope_k_k<<<4096, 256, 0, stream>>>(KVraw, tab, Kb);
  v_trans_k<<<dim3(64, 4, 8), dim3(32, 8), 0, stream>>>(KVraw, Vt);

  attn_k<<<dim3(128, 16, 2), 64, 0, stream>>>(Qb, Kb, Vt, Yb);

  gemm_bt<<<dim3(16, 32), 256, 0, stream>>>(Yb, wprojT, out, 4096, 2048, 2048);
}

// Round 2
// 455.609 us; speedup vs baseline: 1.2566x; 1.2566x over previous
//
#include <hip/hip_runtime.h>
#include <hip/hip_bf16.h>

#define B_ 2
#define T_ 2048
#define C_ 2048
#define H_ 16
#define KH_ 4
#define D_ 128

typedef unsigned short ushort_t;
typedef __attribute__((ext_vector_type(8))) short short8;
typedef __attribute__((ext_vector_type(4))) float f32x4;

#define RSQRT_D 0.08838834764831845f
#define L2E 1.4426950408889634f

__device__ __forceinline__ ushort_t f2b(float f) {
  union { float f; unsigned u; } v; v.f = f;
  unsigned r = v.u + 0x7fffu + ((v.u >> 16) & 1u);
  return (ushort_t)(r >> 16);
}
__device__ __forceinline__ float b2f(ushort_t u) {
  union { unsigned u; float f; } v; v.u = ((unsigned)u) << 16;
  return v.f;
}

__device__ __forceinline__ f32x4 mfma16(short8 a, short8 b, f32x4 c) {
  return __builtin_amdgcn_mfma_f32_16x16x32_bf16(a, b, c, 0, 0, 0);
}

__device__ __forceinline__ void async16(const void* g, void* l) {
  __builtin_amdgcn_global_load_lds(
      (const __attribute__((address_space(1))) void*)g,
      (__attribute__((address_space(3))) void*)l, 16, 0, 0);
}

// ---------------- small prep kernels ----------------

__global__ void convert_f32_bf16(const float* __restrict__ in, ushort_t* __restrict__ out, int n4) {
  int i = blockIdx.x * blockDim.x + threadIdx.x;
  if (i >= n4) return;
  float4 v = ((const float4*)in)[i];
  ushort4 o;
  o.x = f2b(v.x); o.y = f2b(v.y); o.z = f2b(v.z); o.w = f2b(v.w);
  ((ushort4*)out)[i] = o;
}

// out[c][r] = bf16(in[r][c]);  in: R x C f32, out: C x R bf16
__global__ void transpose_to_bf16(const float* __restrict__ in, ushort_t* __restrict__ out, int R, int C) {
  __shared__ float tile[32][33];
  int c0 = blockIdx.x * 32, r0 = blockIdx.y * 32;
  int tx = threadIdx.x, ty = threadIdx.y;
#pragma unroll
  for (int i = 0; i < 4; i++) {
    int r = ty + i * 8;
    tile[r][tx] = in[(size_t)(r0 + r) * C + c0 + tx];
  }
  __syncthreads();
#pragma unroll
  for (int i = 0; i < 4; i++) {
    int r = ty + i * 8;
    out[(size_t)(c0 + r) * R + r0 + tx] = f2b(tile[tx][r]);
  }
}

// cos/sin table: tab[t*64+d] = (cos(t*omega[d]), sin(t*omega[d]))
__global__ void rope_tab_k(const float* __restrict__ omega, float2* __restrict__ tab) {
  int idx = blockIdx.x * blockDim.x + threadIdx.x;  // 2048*64
  int d = idx & 63;
  int t = idx >> 6;
  float ang = (float)t * omega[d];
  tab[idx] = make_float2(cosf(ang), sinf(ang));
}

// Qraw [b*T+t][h*128+d] -> rope -> Qb [(b*16+h)*T + t][d]
__global__ void rope_q_k(const ushort_t* __restrict__ Qraw, const float2* __restrict__ tab,
                         ushort_t* __restrict__ Qb) {
  int idx = blockIdx.x * blockDim.x + threadIdx.x;  // B*T*H*64 = 4194304
  int d = idx & 63;
  int h = (idx >> 6) & 15;
  int t = (idx >> 10) & 2047;
  int b = idx >> 21;
  size_t in_off = ((size_t)(b * 2048 + t) * 16 + h) * 128 + d;
  float x1 = b2f(Qraw[in_off]);
  float x2 = b2f(Qraw[in_off + 64]);
  float2 cs = tab[t * 64 + d];
  size_t out_off = ((size_t)(b * 16 + h) * 2048 + t) * 128 + d;
  Qb[out_off] = f2b(x1 * cs.x - x2 * cs.y);
  Qb[out_off + 64] = f2b(x1 * cs.y + x2 * cs.x);
}

// KVraw cols 0..511 = k -> rope -> Kb [(b*4+kh)*T + t][d]
__global__ void rope_k_k(const ushort_t* __restrict__ KVraw, const float2* __restrict__ tab,
                         ushort_t* __restrict__ Kb) {
  int idx = blockIdx.x * blockDim.x + threadIdx.x;  // B*T*KH*64 = 1048576
  int d = idx & 63;
  int kh = (idx >> 6) & 3;
  int t = (idx >> 8) & 2047;
  int b = idx >> 19;
  size_t in_off = (size_t)(b * 2048 + t) * 1024 + kh * 128 + d;
  float x1 = b2f(KVraw[in_off]);
  float x2 = b2f(KVraw[in_off + 64]);
  float2 cs = tab[t * 64 + d];
  size_t out_off = ((size_t)(b * 4 + kh) * 2048 + t) * 128 + d;
  Kb[out_off] = f2b(x1 * cs.x - x2 * cs.y);
  Kb[out_off + 64] = f2b(x1 * cs.y + x2 * cs.x);
}

// V transpose: KVraw cols 512..1023 -> Vt [(b*4+kh)*128 + d][t]
__global__ void v_trans_k(const ushort_t* __restrict__ KVraw, ushort_t* __restrict__ Vt) {
  __shared__ ushort_t tile[32][33];
  int z = blockIdx.z;        // b*4+kh
  int b = z >> 2, kh = z & 3;
  int d0 = blockIdx.y * 32;
  int t0 = blockIdx.x * 32;
  int tx = threadIdx.x, ty = threadIdx.y;
#pragma unroll
  for (int i = 0; i < 4; i++) {
    int tt = ty + i * 8;
    tile[tt][tx] = KVraw[(size_t)(b * 2048 + t0 + tt) * 1024 + 512 + kh * 128 + d0 + tx];
  }
  __syncthreads();
#pragma unroll
  for (int i = 0; i < 4; i++) {
    int dd = ty + i * 8;
    Vt[((size_t)z * 128 + d0 + dd) * 2048 + t0 + tx] = tile[tx][dd];
  }
}

// ---------------- GEMM: C[M][N] = A[M][K] @ Bt[N][K]^T  (bf16 in, f32 acc) ----------------

__device__ __forceinline__ void store_out(float* C, size_t idx, float v) { C[idx] = v; }
__device__ __forceinline__ void store_out(ushort_t* C, size_t idx, float v) { C[idx] = f2b(v); }

template <typename OUT_T>
__global__ __launch_bounds__(256) void gemm_bt(const ushort_t* __restrict__ A,
                                               const ushort_t* __restrict__ Bt,
                                               OUT_T* __restrict__ C,
                                               int M, int N, int K) {
  __shared__ __attribute__((aligned(16))) ushort_t As[128 * 32];
  __shared__ __attribute__((aligned(16))) ushort_t Bs[128 * 32];
  const int tid = threadIdx.x;
  const int lane = tid & 63;
  const int w = tid >> 6;
  const int bm = blockIdx.y, bn = blockIdx.x;
  const int lr = lane & 15, lc = lane >> 4;
  const int wr = (w >> 1) * 64, wc = (w & 1) * 64;
  const ushort_t* Ab = A + (size_t)bm * 128 * K;
  const ushort_t* Bb = Bt + (size_t)bn * 128 * K;
  const int srow = tid >> 2;
  const int scol = (tid & 3) * 8;
  f32x4 acc[4][4];
#pragma unroll
  for (int i = 0; i < 4; i++)
#pragma unroll
    for (int j = 0; j < 4; j++) acc[i][j] = (f32x4)(0.0f);

  for (int k0 = 0; k0 < K; k0 += 32) {
    async16(Ab + (size_t)srow * K + k0 + scol, As + srow * 32 + scol);
    async16(Ab + (size_t)(srow + 64) * K + k0 + scol, As + (srow + 64) * 32 + scol);
    async16(Bb + (size_t)srow * K + k0 + scol, Bs + srow * 32 + scol);
    async16(Bb + (size_t)(srow + 64) * K + k0 + scol, Bs + (srow + 64) * 32 + scol);
    __syncthreads();
    short8 af[4], bf[4];
#pragma unroll
    for (int mi = 0; mi < 4; mi++)
      af[mi] = *(const short8*)(As + (wr + mi * 16 + lr) * 32 + lc * 8);
#pragma unroll
    for (int ni = 0; ni < 4; ni++)
      bf[ni] = *(const short8*)(Bs + (wc + ni * 16 + lr) * 32 + lc * 8);
#pragma unroll
    for (int mi = 0; mi < 4; mi++)
#pragma unroll
      for (int ni = 0; ni < 4; ni++)
        acc[mi][ni] = mfma16(af[mi], bf[ni], acc[mi][ni]);
    __syncthreads();
  }
#pragma unroll
  for (int mi = 0; mi < 4; mi++) {
#pragma unroll
    for (int ni = 0; ni < 4; ni++) {
      int row = bm * 128 + wr + mi * 16 + lc * 4;
      int col = bn * 128 + wc + ni * 16 + lr;
#pragma unroll
      for (int r = 0; r < 4; r++)
        store_out(C, (size_t)(row + r) * N + col, acc[mi][ni][r]);
    }
  }
}

// ---------------- flash attention (causal GQA) ----------------
// 256 threads = 4 INDEPENDENT waves; wave w handles q-chunk (63 - bx*4 - w)*32..+31.
// No __syncthreads: per-wave private P-LDS, same-wave ds ordering + lgkmcnt.
// Qb: [(b*16+h)*T + t][128], Kb: [(b*4+kh)*T + t][128], Vt: [(b*4+kh)*128 + d][T]
// Yb: [b*T + t][h*128 + d]  (bf16)
__global__ __launch_bounds__(256, 2) void attn_k(const ushort_t* __restrict__ Qb,
                                                 const ushort_t* __restrict__ Kb,
                                                 const ushort_t* __restrict__ Vt,
                                                 ushort_t* __restrict__ Yb) {
  __shared__ __attribute__((aligned(16))) ushort_t p_lds[4][32 * 32];
  const int tid = threadIdx.x;
  const int lane = tid & 63;
  const int w = tid >> 6;
  const int lr = lane & 15, lc = lane >> 4;
  const int h = blockIdx.y;
  const int b = blockIdx.z;
  const int kh = h >> 2;
  const int chunk = 63 - (blockIdx.x * 4 + w);   // heavy chunks dispatched first
  const int q0 = chunk * 32;

  const ushort_t* Qp = Qb + (size_t)(b * 16 + h) * T_ * D_;
  const ushort_t* Kp = Kb + (size_t)(b * 4 + kh) * T_ * D_;
  const ushort_t* Vp = Vt + (size_t)(b * 4 + kh) * D_ * T_;
  ushort_t* pl = p_lds[w];

  short8 qf[2][4];
#pragma unroll
  for (int f = 0; f < 2; f++)
#pragma unroll
    for (int c = 0; c < 4; c++)
      qf[f][c] = *(const short8*)(Qp + (size_t)(q0 + f * 16 + lr) * D_ + c * 32 + lc * 8);

  f32x4 o[2][8];
#pragma unroll
  for (int f = 0; f < 2; f++)
#pragma unroll
    for (int n = 0; n < 8; n++) o[f][n] = (f32x4)(0.0f);
  float m[2][4], lsum[2][4];
#pragma unroll
  for (int f = 0; f < 2; f++)
#pragma unroll
    for (int r = 0; r < 4; r++) { m[f][r] = -1e30f; lsum[f][r] = 0.0f; }

  short8 ones;
#pragma unroll
  for (int j = 0; j < 8; j++) ones[j] = (short)0x3F80;  // bf16 1.0

  const int ntiles = (q0 >> 5) + 1;  // kv tiles of 32

  short8 kA[2][4], kB[2][4];
#pragma unroll
  for (int j = 0; j < 2; j++)
#pragma unroll
    for (int c = 0; c < 4; c++)
      kA[j][c] = *(const short8*)(Kp + (size_t)(j * 16 + lr) * D_ + c * 32 + lc * 8);

  auto tile_step = [&](int ti, short8 (&kc)[2][4], short8 (&kn)[2][4]) {
    const int kv0 = ti * 32;
    // V for this tile — issued early so softmax covers the latency
    short8 vr[8];
#pragma unroll
    for (int n = 0; n < 8; n++)
      vr[n] = *(const short8*)(Vp + (size_t)(n * 16 + lr) * T_ + kv0 + lc * 8);
    // QK^T
    f32x4 s[2][2];
    s[0][0] = (f32x4)(0.0f); s[0][1] = (f32x4)(0.0f);
    s[1][0] = (f32x4)(0.0f); s[1][1] = (f32x4)(0.0f);
#pragma unroll
    for (int c = 0; c < 4; c++) {
#pragma unroll
      for (int f = 0; f < 2; f++) {
        s[f][0] = mfma16(qf[f][c], kc[0][c], s[f][0]);
        s[f][1] = mfma16(qf[f][c], kc[1][c], s[f][1]);
      }
    }
    // prefetch next K tile into kn (register double-buffer)
    if (ti + 1 < ntiles) {
      const int kv1 = kv0 + 32;
#pragma unroll
      for (int j = 0; j < 2; j++)
#pragma unroll
        for (int c = 0; c < 4; c++)
          kn[j][c] = *(const short8*)(Kp + (size_t)(kv1 + j * 16 + lr) * D_ + c * 32 + lc * 8);
    }
    // softmax: rows q = q0 + f*16 + lc*4 + r, cols kv = kv0 + lr (+16)
    const bool last = (ti == ntiles - 1);
    float p[2][2][4], tm[2][4];
#pragma unroll
    for (int f = 0; f < 2; f++) {
#pragma unroll
      for (int r = 0; r < 4; r++) {
        int q = q0 + f * 16 + lc * 4 + r;
        float a0 = s[f][0][r] * RSQRT_D;
        float a1 = s[f][1][r] * RSQRT_D;
        if (last) {
          if (kv0 + lr > q) a0 = -1e30f;
          if (kv0 + 16 + lr > q) a1 = -1e30f;
        }
        p[f][0][r] = a0; p[f][1][r] = a1;
        tm[f][r] = fmaxf(a0, a1);
      }
    }
#pragma unroll
    for (int off = 1; off < 16; off <<= 1)
#pragma unroll
      for (int f = 0; f < 2; f++)
#pragma unroll
        for (int r = 0; r < 4; r++) tm[f][r] = fmaxf(tm[f][r], __shfl_xor(tm[f][r], off));
    float al[2][4];
#pragma unroll
    for (int f = 0; f < 2; f++) {
#pragma unroll
      for (int r = 0; r < 4; r++) {
        float mn = fmaxf(m[f][r], tm[f][r]);
        al[f][r] = exp2f((m[f][r] - mn) * L2E);
        m[f][r] = mn;
        p[f][0][r] = exp2f((p[f][0][r] - mn) * L2E);
        p[f][1][r] = exp2f((p[f][1][r] - mn) * L2E);
      }
    }
    // bounce P through wave-private LDS to A-fragment layout
#pragma unroll
    for (int f = 0; f < 2; f++)
#pragma unroll
      for (int r = 0; r < 4; r++) {
        pl[(f * 16 + lc * 4 + r) * 32 + lr] = f2b(p[f][0][r]);
        pl[(f * 16 + lc * 4 + r) * 32 + lr + 16] = f2b(p[f][1][r]);
      }
    short8 pf[2];
#pragma unroll
    for (int f = 0; f < 2; f++)
      pf[f] = *(const short8*)(pl + (f * 16 + lr) * 32 + lc * 8);
    // row sums via MFMA against ones (C rows match m/lsum layout)
#pragma unroll
    for (int f = 0; f < 2; f++) {
      f32x4 rs = mfma16(pf[f], ones, (f32x4)(0.0f));
#pragma unroll
      for (int r = 0; r < 4; r++) lsum[f][r] = lsum[f][r] * al[f][r] + rs[r];
    }
    // rescale O and accumulate PV
#pragma unroll
    for (int f = 0; f < 2; f++)
#pragma unroll
      for (int n = 0; n < 8; n++)
#pragma unroll
        for (int r = 0; r < 4; r++) o[f][n][r] *= al[f][r];
#pragma unroll
    for (int n = 0; n < 8; n++)
#pragma unroll
      for (int f = 0; f < 2; f++) o[f][n] = mfma16(pf[f], vr[n], o[f][n]);
  };

  for (int ti = 0; ti < ntiles; ti += 2) {
    tile_step(ti, kA, kB);
    if (ti + 1 < ntiles) tile_step(ti + 1, kB, kA);
  }

  float inv[2][4];
#pragma unroll
  for (int f = 0; f < 2; f++)
#pragma unroll
    for (int r = 0; r < 4; r++) inv[f][r] = 1.0f / lsum[f][r];
#pragma unroll
  for (int f = 0; f < 2; f++)
#pragma unroll
    for (int n = 0; n < 8; n++)
#pragma unroll
      for (int r = 0; r < 4; r++) {
        int q = q0 + f * 16 + lc * 4 + r;
        int d = n * 16 + lr;
        Yb[(size_t)(b * T_ + q) * 2048 + h * 128 + d] = f2b(o[f][n][r] * inv[f][r]);
      }
}

// ---------------- launch ----------------

extern "C" void kernel_launch(void* const* d_in, const int* in_sizes, int n_in,
                              void* d_out, int out_size, void* d_ws, size_t ws_size,
                              hipStream_t stream) {
  (void)in_sizes; (void)n_in; (void)out_size; (void)ws_size;
  const float* x = (const float*)d_in[0];
  const float* wq = (const float*)d_in[1];
  const float* wkv = (const float*)d_in[2];
  const float* wproj = (const float*)d_in[3];
  const float* omega = (const float*)d_in[4];
  float* out = (float*)d_out;
  char* ws = (char*)d_ws;

  ushort_t* xb     = (ushort_t*)(ws + 0);          // 4096x2048 bf16 = 16.8MB
  ushort_t* wqT    = (ushort_t*)(ws + 16777216);   // 2048x2048 bf16
  ushort_t* wkvT   = (ushort_t*)(ws + 25165824);   // 1024x2048 bf16
  ushort_t* wprojT = (ushort_t*)(ws + 29360128);   // 2048x2048 bf16
  ushort_t* Qraw   = (ushort_t*)(ws + 37748736);   // 4096x2048 bf16
  ushort_t* KVraw  = (ushort_t*)(ws + 54525952);   // 4096x1024 bf16
  ushort_t* Qb     = (ushort_t*)(ws + 62914560);   // [b][h][t][d] bf16
  ushort_t* Kb     = (ushort_t*)(ws + 79691776);   // [b][kh][t][d] bf16
  ushort_t* Vt     = (ushort_t*)(ws + 83886080);   // [b][kh][d][t] bf16
  ushort_t* Yb     = (ushort_t*)(ws + 88080384);   // 4096x2048 bf16
  float2*   tab    = (float2*)(ws + 104857600);    // 2048x64 float2 = 1MB

  convert_f32_bf16<<<8192, 256, 0, stream>>>(x, xb, 2097152);
  transpose_to_bf16<<<dim3(64, 64), dim3(32, 8), 0, stream>>>(wq, wqT, 2048, 2048);
  transpose_to_bf16<<<dim3(32, 64), dim3(32, 8), 0, stream>>>(wkv, wkvT, 2048, 1024);
  transpose_to_bf16<<<dim3(64, 64), dim3(32, 8), 0, stream>>>(wproj, wprojT, 2048, 2048);
  rope_tab_k<<<512, 256, 0, stream>>>(omega, tab);

  gemm_bt<<<dim3(16, 32), 256, 0, stream>>>(xb, wqT, Qraw, 4096, 2048, 2048);
  gemm_bt<<<dim3(8, 32), 256, 0, stream>>>(xb, wkvT, KVraw, 4096, 1024, 2048);

  rope_q_k<<<16384, 256, 0, stream>>>(Qraw, tab, Qb);
  rope_k_k<<<4096, 256, 0, stream>>>(KVraw, tab, Kb);
  v_trans_k<<<dim3(64, 4, 8), dim3(32, 8), 0, stream>>>(KVraw, Vt);

  attn_k<<<dim3(16, 16, 2), 256, 0, stream>>>(Qb, Kb, Vt, Yb);

  gemm_bt<<<dim3(16, 32), 256, 0, stream>>>(Yb, wprojT, out, 4096, 2048, 2048);
}

// Round 3
// 417.636 us; speedup vs baseline: 1.3708x; 1.0909x over previous
//
#include <hip/hip_runtime.h>
#include <hip/hip_bf16.h>

#define B_ 2
#define T_ 2048
#define C_ 2048
#define H_ 16
#define KH_ 4
#define D_ 128

typedef unsigned short ushort_t;
typedef __attribute__((ext_vector_type(8))) short short8;
typedef __attribute__((ext_vector_type(4))) float f32x4;

#define RSQRT_D 0.08838834764831845f
#define L2E 1.4426950408889634f

__device__ __forceinline__ ushort_t f2b(float f) {
  union { float f; unsigned u; } v; v.f = f;
  unsigned r = v.u + 0x7fffu + ((v.u >> 16) & 1u);
  return (ushort_t)(r >> 16);
}
__device__ __forceinline__ float b2f(ushort_t u) {
  union { unsigned u; float f; } v; v.u = ((unsigned)u) << 16;
  return v.f;
}

__device__ __forceinline__ f32x4 mfma16(short8 a, short8 b, f32x4 c) {
  return __builtin_amdgcn_mfma_f32_16x16x32_bf16(a, b, c, 0, 0, 0);
}

__device__ __forceinline__ void async16(const void* g, void* l) {
  __builtin_amdgcn_global_load_lds(
      (const __attribute__((address_space(1))) void*)g,
      (__attribute__((address_space(3))) void*)l, 16, 0, 0);
}

// ---------------- small prep kernels ----------------

__global__ void convert_f32_bf16(const float* __restrict__ in, ushort_t* __restrict__ out, int n4) {
  int i = blockIdx.x * blockDim.x + threadIdx.x;
  if (i >= n4) return;
  float4 v = ((const float4*)in)[i];
  ushort4 o;
  o.x = f2b(v.x); o.y = f2b(v.y); o.z = f2b(v.z); o.w = f2b(v.w);
  ((ushort4*)out)[i] = o;
}

// out[c][r] = bf16(in[r][c]);  in: R x C f32, out: C x R bf16
__global__ void transpose_to_bf16(const float* __restrict__ in, ushort_t* __restrict__ out, int R, int C) {
  __shared__ float tile[32][33];
  int c0 = blockIdx.x * 32, r0 = blockIdx.y * 32;
  int tx = threadIdx.x, ty = threadIdx.y;
#pragma unroll
  for (int i = 0; i < 4; i++) {
    int r = ty + i * 8;
    tile[r][tx] = in[(size_t)(r0 + r) * C + c0 + tx];
  }
  __syncthreads();
#pragma unroll
  for (int i = 0; i < 4; i++) {
    int r = ty + i * 8;
    out[(size_t)(c0 + r) * R + r0 + tx] = f2b(tile[tx][r]);
  }
}

// cos/sin table: tab[t*64+d] = (cos(t*omega[d]), sin(t*omega[d]))
__global__ void rope_tab_k(const float* __restrict__ omega, float2* __restrict__ tab) {
  int idx = blockIdx.x * blockDim.x + threadIdx.x;  // 2048*64
  int d = idx & 63;
  int t = idx >> 6;
  float ang = (float)t * omega[d];
  tab[idx] = make_float2(cosf(ang), sinf(ang));
}

// Qraw [b*T+t][h*128+d] -> rope -> Qb [(b*16+h)*T + t][d]
__global__ void rope_q_k(const ushort_t* __restrict__ Qraw, const float2* __restrict__ tab,
                         ushort_t* __restrict__ Qb) {
  int idx = blockIdx.x * blockDim.x + threadIdx.x;  // B*T*H*64 = 4194304
  int d = idx & 63;
  int h = (idx >> 6) & 15;
  int t = (idx >> 10) & 2047;
  int b = idx >> 21;
  size_t in_off = ((size_t)(b * 2048 + t) * 16 + h) * 128 + d;
  float x1 = b2f(Qraw[in_off]);
  float x2 = b2f(Qraw[in_off + 64]);
  float2 cs = tab[t * 64 + d];
  size_t out_off = ((size_t)(b * 16 + h) * 2048 + t) * 128 + d;
  Qb[out_off] = f2b(x1 * cs.x - x2 * cs.y);
  Qb[out_off + 64] = f2b(x1 * cs.y + x2 * cs.x);
}

// KVraw cols 0..511 = k -> rope -> Kb [(b*4+kh)*T + t][d]
__global__ void rope_k_k(const ushort_t* __restrict__ KVraw, const float2* __restrict__ tab,
                         ushort_t* __restrict__ Kb) {
  int idx = blockIdx.x * blockDim.x + threadIdx.x;  // B*T*KH*64 = 1048576
  int d = idx & 63;
  int kh = (idx >> 6) & 3;
  int t = (idx >> 8) & 2047;
  int b = idx >> 19;
  size_t in_off = (size_t)(b * 2048 + t) * 1024 + kh * 128 + d;
  float x1 = b2f(KVraw[in_off]);
  float x2 = b2f(KVraw[in_off + 64]);
  float2 cs = tab[t * 64 + d];
  size_t out_off = ((size_t)(b * 4 + kh) * 2048 + t) * 128 + d;
  Kb[out_off] = f2b(x1 * cs.x - x2 * cs.y);
  Kb[out_off + 64] = f2b(x1 * cs.y + x2 * cs.x);
}

// V transpose: KVraw cols 512..1023 -> Vt [(b*4+kh)*128 + d][t]
__global__ void v_trans_k(const ushort_t* __restrict__ KVraw, ushort_t* __restrict__ Vt) {
  __shared__ ushort_t tile[32][33];
  int z = blockIdx.z;        // b*4+kh
  int b = z >> 2, kh = z & 3;
  int d0 = blockIdx.y * 32;
  int t0 = blockIdx.x * 32;
  int tx = threadIdx.x, ty = threadIdx.y;
#pragma unroll
  for (int i = 0; i < 4; i++) {
    int tt = ty + i * 8;
    tile[tt][tx] = KVraw[(size_t)(b * 2048 + t0 + tt) * 1024 + 512 + kh * 128 + d0 + tx];
  }
  __syncthreads();
#pragma unroll
  for (int i = 0; i < 4; i++) {
    int dd = ty + i * 8;
    Vt[((size_t)z * 128 + d0 + dd) * 2048 + t0 + tx] = tile[tx][dd];
  }
}

// ---------------- GEMM: C[M][N] = A[M][K] @ Bt[N][K]^T  (bf16 in, f32 acc) ----------------

__device__ __forceinline__ void store_out(float* C, size_t idx, float v) { C[idx] = v; }
__device__ __forceinline__ void store_out(ushort_t* C, size_t idx, float v) { C[idx] = f2b(v); }

template <typename OUT_T>
__global__ __launch_bounds__(256) void gemm_bt(const ushort_t* __restrict__ A,
                                               const ushort_t* __restrict__ Bt,
                                               OUT_T* __restrict__ C,
                                               int M, int N, int K) {
  __shared__ __attribute__((aligned(16))) ushort_t As[128 * 32];
  __shared__ __attribute__((aligned(16))) ushort_t Bs[128 * 32];
  const int tid = threadIdx.x;
  const int lane = tid & 63;
  const int w = tid >> 6;
  const int bm = blockIdx.y, bn = blockIdx.x;
  const int lr = lane & 15, lc = lane >> 4;
  const int wr = (w >> 1) * 64, wc = (w & 1) * 64;
  const ushort_t* Ab = A + (size_t)bm * 128 * K;
  const ushort_t* Bb = Bt + (size_t)bn * 128 * K;
  const int srow = tid >> 2;
  const int scol = (tid & 3) * 8;
  f32x4 acc[4][4];
#pragma unroll
  for (int i = 0; i < 4; i++)
#pragma unroll
    for (int j = 0; j < 4; j++) acc[i][j] = (f32x4)(0.0f);

  for (int k0 = 0; k0 < K; k0 += 32) {
    async16(Ab + (size_t)srow * K + k0 + scol, As + srow * 32 + scol);
    async16(Ab + (size_t)(srow + 64) * K + k0 + scol, As + (srow + 64) * 32 + scol);
    async16(Bb + (size_t)srow * K + k0 + scol, Bs + srow * 32 + scol);
    async16(Bb + (size_t)(srow + 64) * K + k0 + scol, Bs + (srow + 64) * 32 + scol);
    __syncthreads();
    short8 af[4], bf[4];
#pragma unroll
    for (int mi = 0; mi < 4; mi++)
      af[mi] = *(const short8*)(As + (wr + mi * 16 + lr) * 32 + lc * 8);
#pragma unroll
    for (int ni = 0; ni < 4; ni++)
      bf[ni] = *(const short8*)(Bs + (wc + ni * 16 + lr) * 32 + lc * 8);
#pragma unroll
    for (int mi = 0; mi < 4; mi++)
#pragma unroll
      for (int ni = 0; ni < 4; ni++)
        acc[mi][ni] = mfma16(af[mi], bf[ni], acc[mi][ni]);
    __syncthreads();
  }
#pragma unroll
  for (int mi = 0; mi < 4; mi++) {
#pragma unroll
    for (int ni = 0; ni < 4; ni++) {
      int row = bm * 128 + wr + mi * 16 + lc * 4;
      int col = bn * 128 + wc + ni * 16 + lr;
#pragma unroll
      for (int r = 0; r < 4; r++)
        store_out(C, (size_t)(row + r) * N + col, acc[mi][ni][r]);
    }
  }
}

// ---------------- flash attention (causal GQA) ----------------
// 256 threads = 4 waves cooperating on a 128-row q-block (wave w: rows qb*128+w*32..+31).
// K staged in LDS (KVBLK=64, double-buffered, XOR-swizzled chunk^(row&7)); V in registers.
// Qb: [(b*16+h)*T + t][128], Kb: [(b*4+kh)*T + t][128], Vt: [(b*4+kh)*128 + d][T]
// Yb: [b*T + t][h*128 + d]  (bf16)
__global__ __launch_bounds__(256, 1) void attn_k(const ushort_t* __restrict__ Qb,
                                                 const ushort_t* __restrict__ Kb,
                                                 const ushort_t* __restrict__ Vt,
                                                 ushort_t* __restrict__ Yb) {
  __shared__ __attribute__((aligned(16))) ushort_t Ks[2][64 * 128];  // 32 KB, swizzled
  __shared__ __attribute__((aligned(16))) ushort_t pl[4][32 * 64];   // 16 KB, swizzled
  const int tid = threadIdx.x;
  const int lane = tid & 63;
  const int w = tid >> 6;
  const int lr = lane & 15, lc = lane >> 4;
  const int h = blockIdx.y;
  const int b = blockIdx.z;
  const int kh = h >> 2;
  // complementary pairing: CU's two resident blocks (bz=0/1) get qb and 15-qb
  const int qb = (b == 0) ? (15 - blockIdx.x) : blockIdx.x;
  const int q0w = qb * 128 + w * 32;

  const ushort_t* Qp = Qb + (size_t)(b * 16 + h) * T_ * D_;
  const ushort_t* Kp = Kb + (size_t)(b * 4 + kh) * T_ * D_;
  const ushort_t* Vp = Vt + (size_t)(b * 4 + kh) * D_ * T_;
  ushort_t* plw = pl[w];

  // staging geometry: issue i (0..3): row = i*16 + tid/16, slot cc' = tid%16
  const int st_row = tid >> 4;       // + i*16
  const int st_slot = tid & 15;

  short8 qf[2][4];
#pragma unroll
  for (int f = 0; f < 2; f++)
#pragma unroll
    for (int c = 0; c < 4; c++)
      qf[f][c] = *(const short8*)(Qp + (size_t)(q0w + f * 16 + lr) * D_ + c * 32 + lc * 8);

  f32x4 o[2][8];
#pragma unroll
  for (int f = 0; f < 2; f++)
#pragma unroll
    for (int n = 0; n < 8; n++) o[f][n] = (f32x4)(0.0f);
  float m[2][4], lsum[2][4];
#pragma unroll
  for (int f = 0; f < 2; f++)
#pragma unroll
    for (int r = 0; r < 4; r++) { m[f][r] = -1e30f; lsum[f][r] = 0.0f; }

  short8 ones;
#pragma unroll
  for (int j = 0; j < 8; j++) ones[j] = (short)0x3F80;  // bf16 1.0

  const int nt = qb * 2 + 2;  // kv tiles of 64

  // stage tile 0 into buffer 0
#pragma unroll
  for (int i = 0; i < 4; i++) {
    int row = i * 16 + st_row;
    async16(Kp + (size_t)row * D_ + ((st_slot ^ (row & 7)) * 8),
            &Ks[0][0] + row * 128 + st_slot * 8);
  }

  for (int ti = 0; ti < nt; ti++) {
    __syncthreads();  // drains vmcnt: K[ti] resident; all waves done with other buffer
    const int kv0 = ti * 64;
    if (ti + 1 < nt) {
      const ushort_t* Kn = Kp + (size_t)(kv0 + 64) * D_;
      ushort_t* dst = &Ks[(ti + 1) & 1][0];
#pragma unroll
      for (int i = 0; i < 4; i++) {
        int row = i * 16 + st_row;
        async16(Kn + (size_t)row * D_ + ((st_slot ^ (row & 7)) * 8),
                dst + row * 128 + st_slot * 8);
      }
    }
    if (kv0 <= q0w + 31) {  // wave-active
      const ushort_t* Kl = &Ks[ti & 1][0];
      // V first half — issue early, hidden under QK
      short8 vr0[8];
#pragma unroll
      for (int n = 0; n < 8; n++)
        vr0[n] = *(const short8*)(Vp + (size_t)(n * 16 + lr) * T_ + kv0 + lc * 8);
      // QK^T: S[32 q][64 kv]
      f32x4 s[2][4];
#pragma unroll
      for (int f = 0; f < 2; f++)
#pragma unroll
        for (int kj = 0; kj < 4; kj++) s[f][kj] = (f32x4)(0.0f);
#pragma unroll
      for (int c = 0; c < 4; c++) {
        short8 kf[4];
#pragma unroll
        for (int kj = 0; kj < 4; kj++)
          kf[kj] = *(const short8*)(Kl + (kj * 16 + lr) * 128 + (((c * 4 + lc) ^ (lr & 7)) * 8));
#pragma unroll
        for (int f = 0; f < 2; f++)
#pragma unroll
          for (int kj = 0; kj < 4; kj++)
            s[f][kj] = mfma16(qf[f][c], kf[kj], s[f][kj]);
      }
      // V second half — issue now, hidden under softmax
      short8 vr1[8];
#pragma unroll
      for (int n = 0; n < 8; n++)
        vr1[n] = *(const short8*)(Vp + (size_t)(n * 16 + lr) * T_ + kv0 + 32 + lc * 8);
      // softmax: rows q = q0w + f*16 + lc*4 + r; cols kv = kv0 + kj*16 + lr
      const bool maskt = (kv0 + 63 > q0w);
      float p[2][4][4], tm[2][4];
#pragma unroll
      for (int f = 0; f < 2; f++) {
#pragma unroll
        for (int r = 0; r < 4; r++) {
          const int q = q0w + f * 16 + lc * 4 + r;
          float mx = -1e30f;
#pragma unroll
          for (int kj = 0; kj < 4; kj++) {
            float a = s[f][kj][r] * RSQRT_D;
            if (maskt && (kv0 + kj * 16 + lr > q)) a = -1e30f;
            p[f][kj][r] = a;
            mx = fmaxf(mx, a);
          }
          tm[f][r] = mx;
        }
      }
#pragma unroll
      for (int off = 1; off < 16; off <<= 1)
#pragma unroll
        for (int f = 0; f < 2; f++)
#pragma unroll
          for (int r = 0; r < 4; r++) tm[f][r] = fmaxf(tm[f][r], __shfl_xor(tm[f][r], off));
      float al[2][4];
#pragma unroll
      for (int f = 0; f < 2; f++)
#pragma unroll
        for (int r = 0; r < 4; r++) {
          float mn = fmaxf(m[f][r], tm[f][r]);
          al[f][r] = exp2f((m[f][r] - mn) * L2E);
          m[f][r] = mn;
#pragma unroll
          for (int kj = 0; kj < 4; kj++)
            p[f][kj][r] = exp2f((p[f][kj][r] - mn) * L2E);
        }
      // write P to swizzled LDS: row rp, col kj*16+lr -> chunk 2kj+(lr>>3), ^(rp&7)
#pragma unroll
      for (int f = 0; f < 2; f++)
#pragma unroll
        for (int r = 0; r < 4; r++) {
          const int rp = f * 16 + lc * 4 + r;
#pragma unroll
          for (int kj = 0; kj < 4; kj++)
            plw[rp * 64 + (((2 * kj + (lr >> 3)) ^ (rp & 7)) * 8) + (lr & 7)] = f2b(p[f][kj][r]);
        }
      // read P A-frags; rescale O; rowsum + PV
      short8 pf[2][2];
#pragma unroll
      for (int f = 0; f < 2; f++)
#pragma unroll
        for (int kc = 0; kc < 2; kc++)
          pf[f][kc] = *(const short8*)(plw + (f * 16 + lr) * 64 + (((4 * kc + lc) ^ (lr & 7)) * 8));
#pragma unroll
      for (int f = 0; f < 2; f++)
#pragma unroll
        for (int n = 0; n < 8; n++)
#pragma unroll
          for (int r = 0; r < 4; r++) o[f][n][r] *= al[f][r];
#pragma unroll
      for (int f = 0; f < 2; f++) {
        f32x4 rs = mfma16(pf[f][0], ones, (f32x4)(0.0f));
        rs = mfma16(pf[f][1], ones, rs);
#pragma unroll
        for (int r = 0; r < 4; r++) lsum[f][r] = lsum[f][r] * al[f][r] + rs[r];
      }
#pragma unroll
      for (int n = 0; n < 8; n++)
#pragma unroll
        for (int f = 0; f < 2; f++) o[f][n] = mfma16(pf[f][0], vr0[n], o[f][n]);
#pragma unroll
      for (int n = 0; n < 8; n++)
#pragma unroll
        for (int f = 0; f < 2; f++) o[f][n] = mfma16(pf[f][1], vr1[n], o[f][n]);
    }
  }

  float inv[2][4];
#pragma unroll
  for (int f = 0; f < 2; f++)
#pragma unroll
    for (int r = 0; r < 4; r++) inv[f][r] = 1.0f / lsum[f][r];
#pragma unroll
  for (int f = 0; f < 2; f++)
#pragma unroll
    for (int n = 0; n < 8; n++)
#pragma unroll
      for (int r = 0; r < 4; r++) {
        int q = q0w + f * 16 + lc * 4 + r;
        int d = n * 16 + lr;
        Yb[(size_t)(b * T_ + q) * 2048 + h * 128 + d] = f2b(o[f][n][r] * inv[f][r]);
      }
}

// ---------------- launch ----------------

extern "C" void kernel_launch(void* const* d_in, const int* in_sizes, int n_in,
                              void* d_out, int out_size, void* d_ws, size_t ws_size,
                              hipStream_t stream) {
  (void)in_sizes; (void)n_in; (void)out_size; (void)ws_size;
  const float* x = (const float*)d_in[0];
  const float* wq = (const float*)d_in[1];
  const float* wkv = (const float*)d_in[2];
  const float* wproj = (const float*)d_in[3];
  const float* omega = (const float*)d_in[4];
  float* out = (float*)d_out;
  char* ws = (char*)d_ws;

  ushort_t* xb     = (ushort_t*)(ws + 0);          // 4096x2048 bf16 = 16.8MB
  ushort_t* wqT    = (ushort_t*)(ws + 16777216);   // 2048x2048 bf16
  ushort_t* wkvT   = (ushort_t*)(ws + 25165824);   // 1024x2048 bf16
  ushort_t* wprojT = (ushort_t*)(ws + 29360128);   // 2048x2048 bf16
  ushort_t* Qraw   = (ushort_t*)(ws + 37748736);   // 4096x2048 bf16
  ushort_t* KVraw  = (ushort_t*)(ws + 54525952);   // 4096x1024 bf16
  ushort_t* Qb     = (ushort_t*)(ws + 62914560);   // [b][h][t][d] bf16
  ushort_t* Kb     = (ushort_t*)(ws + 79691776);   // [b][kh][t][d] bf16
  ushort_t* Vt     = (ushort_t*)(ws + 83886080);   // [b][kh][d][t] bf16
  ushort_t* Yb     = (ushort_t*)(ws + 88080384);   // 4096x2048 bf16
  float2*   tab    = (float2*)(ws + 104857600);    // 2048x64 float2 = 1MB

  convert_f32_bf16<<<8192, 256, 0, stream>>>(x, xb, 2097152);
  transpose_to_bf16<<<dim3(64, 64), dim3(32, 8), 0, stream>>>(wq, wqT, 2048, 2048);
  transpose_to_bf16<<<dim3(32, 64), dim3(32, 8), 0, stream>>>(wkv, wkvT, 2048, 1024);
  transpose_to_bf16<<<dim3(64, 64), dim3(32, 8), 0, stream>>>(wproj, wprojT, 2048, 2048);
  rope_tab_k<<<512, 256, 0, stream>>>(omega, tab);

  gemm_bt<<<dim3(16, 32), 256, 0, stream>>>(xb, wqT, Qraw, 4096, 2048, 2048);
  gemm_bt<<<dim3(8, 32), 256, 0, stream>>>(xb, wkvT, KVraw, 4096, 1024, 2048);

  rope_q_k<<<16384, 256, 0, stream>>>(Qraw, tab, Qb);
  rope_k_k<<<4096, 256, 0, stream>>>(KVraw, tab, Kb);
  v_trans_k<<<dim3(64, 4, 8), dim3(32, 8), 0, stream>>>(KVraw, Vt);

  attn_k<<<dim3(16, 16, 2), 256, 0, stream>>>(Qb, Kb, Vt, Yb);

  gemm_bt<<<dim3(16, 32), 256, 0, stream>>>(Yb, wprojT, out, 4096, 2048, 2048);
}

// Round 4
// 274.133 us; speedup vs baseline: 2.0885x; 1.5235x over previous
//
#include <hip/hip_runtime.h>
#include <hip/hip_bf16.h>

#define B_ 2
#define T_ 2048
#define C_ 2048
#define H_ 16
#define KH_ 4
#define D_ 128

typedef unsigned short ushort_t;
typedef __attribute__((ext_vector_type(8))) short short8;
typedef __attribute__((ext_vector_type(4))) float f32x4;

#define RSQRT_D 0.08838834764831845f
#define L2E 1.4426950408889634f

__device__ __forceinline__ ushort_t f2b(float f) {
  union { float f; unsigned u; } v; v.f = f;
  unsigned r = v.u + 0x7fffu + ((v.u >> 16) & 1u);
  return (ushort_t)(r >> 16);
}
__device__ __forceinline__ float b2f(ushort_t u) {
  union { unsigned u; float f; } v; v.u = ((unsigned)u) << 16;
  return v.f;
}

__device__ __forceinline__ f32x4 mfma16(short8 a, short8 b, f32x4 c) {
  return __builtin_amdgcn_mfma_f32_16x16x32_bf16(a, b, c, 0, 0, 0);
}

__device__ __forceinline__ void async16(const void* g, void* l) {
  __builtin_amdgcn_global_load_lds(
      (const __attribute__((address_space(1))) void*)g,
      (__attribute__((address_space(3))) void*)l, 16, 0, 0);
}

// packed f32x2 -> bf16x2 (RTNE); dst.lo = bf16(lo), dst.hi = bf16(hi)
__device__ __forceinline__ unsigned cvtpk(float lo, float hi) {
  unsigned r;
  asm volatile("v_cvt_pk_bf16_f32 %0, %1, %2" : "=v"(r) : "v"(lo), "v"(hi));
  return r;
}

// ---------------- small prep kernels ----------------

__global__ void convert_f32_bf16(const float* __restrict__ in, ushort_t* __restrict__ out, int n4) {
  int i = blockIdx.x * blockDim.x + threadIdx.x;
  if (i >= n4) return;
  float4 v = ((const float4*)in)[i];
  ushort4 o;
  o.x = f2b(v.x); o.y = f2b(v.y); o.z = f2b(v.z); o.w = f2b(v.w);
  ((ushort4*)out)[i] = o;
}

// out[c][r] = bf16(in[r][c]);  in: R x C f32, out: C x R bf16
__global__ void transpose_to_bf16(const float* __restrict__ in, ushort_t* __restrict__ out, int R, int C) {
  __shared__ float tile[32][33];
  int c0 = blockIdx.x * 32, r0 = blockIdx.y * 32;
  int tx = threadIdx.x, ty = threadIdx.y;
#pragma unroll
  for (int i = 0; i < 4; i++) {
    int r = ty + i * 8;
    tile[r][tx] = in[(size_t)(r0 + r) * C + c0 + tx];
  }
  __syncthreads();
#pragma unroll
  for (int i = 0; i < 4; i++) {
    int r = ty + i * 8;
    out[(size_t)(c0 + r) * R + r0 + tx] = f2b(tile[tx][r]);
  }
}

// cos/sin table: tab[t*64+d] = (cos(t*omega[d]), sin(t*omega[d]))
__global__ void rope_tab_k(const float* __restrict__ omega, float2* __restrict__ tab) {
  int idx = blockIdx.x * blockDim.x + threadIdx.x;  // 2048*64
  int d = idx & 63;
  int t = idx >> 6;
  float ang = (float)t * omega[d];
  tab[idx] = make_float2(cosf(ang), sinf(ang));
}

// Qraw [b*T+t][h*128+d] -> rope -> Qb [(b*16+h)*T + t][d]
__global__ void rope_q_k(const ushort_t* __restrict__ Qraw, const float2* __restrict__ tab,
                         ushort_t* __restrict__ Qb) {
  int idx = blockIdx.x * blockDim.x + threadIdx.x;  // B*T*H*64 = 4194304
  int d = idx & 63;
  int h = (idx >> 6) & 15;
  int t = (idx >> 10) & 2047;
  int b = idx >> 21;
  size_t in_off = ((size_t)(b * 2048 + t) * 16 + h) * 128 + d;
  float x1 = b2f(Qraw[in_off]);
  float x2 = b2f(Qraw[in_off + 64]);
  float2 cs = tab[t * 64 + d];
  size_t out_off = ((size_t)(b * 16 + h) * 2048 + t) * 128 + d;
  Qb[out_off] = f2b(x1 * cs.x - x2 * cs.y);
  Qb[out_off + 64] = f2b(x1 * cs.y + x2 * cs.x);
}

// KVraw cols 0..511 = k -> rope -> Kb [(b*4+kh)*T + t][d]
__global__ void rope_k_k(const ushort_t* __restrict__ KVraw, const float2* __restrict__ tab,
                         ushort_t* __restrict__ Kb) {
  int idx = blockIdx.x * blockDim.x + threadIdx.x;  // B*T*KH*64 = 1048576
  int d = idx & 63;
  int kh = (idx >> 6) & 3;
  int t = (idx >> 8) & 2047;
  int b = idx >> 19;
  size_t in_off = (size_t)(b * 2048 + t) * 1024 + kh * 128 + d;
  float x1 = b2f(KVraw[in_off]);
  float x2 = b2f(KVraw[in_off + 64]);
  float2 cs = tab[t * 64 + d];
  size_t out_off = ((size_t)(b * 4 + kh) * 2048 + t) * 128 + d;
  Kb[out_off] = f2b(x1 * cs.x - x2 * cs.y);
  Kb[out_off + 64] = f2b(x1 * cs.y + x2 * cs.x);
}

// V fragment pre-pack: Vf short8 index = (((z*32+tile)*2+hv)*8+n)*64 + lane
// element j of that short8 = V[b][t = tile*64 + kl][kh][d = n*16 + (lane&15)]
// kl = (hv*2 + ((j>>1)>>1))*16 + (lane>>4)*4 + 2*((j>>1)&1) + (j&1)
// This is the exact MFMA B-frag k-slot order matching the attn kernel's
// in-register P packing (zero-shuffle PV).
__global__ void v_frag_k(const ushort_t* __restrict__ KVraw, ushort_t* __restrict__ Vf) {
  int idx = blockIdx.x * blockDim.x + threadIdx.x;  // 262144 short8 units
  int lane = idx & 63;
  int n = (idx >> 6) & 7;
  int hv = (idx >> 9) & 1;
  int tile = (idx >> 10) & 31;
  int z = idx >> 15;  // b*4+kh
  int b = z >> 2, kh = z & 3;
  int lr = lane & 15, lc = lane >> 4;
  int d = n * 16 + lr;
  union { ushort_t u[8]; short8 v; } out;
#pragma unroll
  for (int j = 0; j < 8; j++) {
    int tw = j >> 1, par = j & 1;
    int kl = (hv * 2 + (tw >> 1)) * 16 + lc * 4 + 2 * (tw & 1) + par;
    int t = tile * 64 + kl;
    out.u[j] = KVraw[(size_t)(b * 2048 + t) * 1024 + 512 + kh * 128 + d];
  }
  *(short8*)(Vf + (size_t)idx * 8) = out.v;
}

// ---------------- GEMM: C[M][N] = A[M][K] @ Bt[N][K]^T  (bf16 in, f32 acc) ----------------

__device__ __forceinline__ void store_out(float* C, size_t idx, float v) { C[idx] = v; }
__device__ __forceinline__ void store_out(ushort_t* C, size_t idx, float v) { C[idx] = f2b(v); }

template <typename OUT_T>
__global__ __launch_bounds__(256) void gemm_bt(const ushort_t* __restrict__ A,
                                               const ushort_t* __restrict__ Bt,
                                               OUT_T* __restrict__ C,
                                               int M, int N, int K) {
  __shared__ __attribute__((aligned(16))) ushort_t As[128 * 32];
  __shared__ __attribute__((aligned(16))) ushort_t Bs[128 * 32];
  const int tid = threadIdx.x;
  const int lane = tid & 63;
  const int w = tid >> 6;
  const int bm = blockIdx.y, bn = blockIdx.x;
  const int lr = lane & 15, lc = lane >> 4;
  const int wr = (w >> 1) * 64, wc = (w & 1) * 64;
  const ushort_t* Ab = A + (size_t)bm * 128 * K;
  const ushort_t* Bb = Bt + (size_t)bn * 128 * K;
  const int srow = tid >> 2;
  const int scol = (tid & 3) * 8;
  f32x4 acc[4][4];
#pragma unroll
  for (int i = 0; i < 4; i++)
#pragma unroll
    for (int j = 0; j < 4; j++) acc[i][j] = (f32x4)(0.0f);

  for (int k0 = 0; k0 < K; k0 += 32) {
    async16(Ab + (size_t)srow * K + k0 + scol, As + srow * 32 + scol);
    async16(Ab + (size_t)(srow + 64) * K + k0 + scol, As + (srow + 64) * 32 + scol);
    async16(Bb + (size_t)srow * K + k0 + scol, Bs + srow * 32 + scol);
    async16(Bb + (size_t)(srow + 64) * K + k0 + scol, Bs + (srow + 64) * 32 + scol);
    __syncthreads();
    short8 af[4], bf[4];
#pragma unroll
    for (int mi = 0; mi < 4; mi++)
      af[mi] = *(const short8*)(As + (wr + mi * 16 + lr) * 32 + lc * 8);
#pragma unroll
    for (int ni = 0; ni < 4; ni++)
      bf[ni] = *(const short8*)(Bs + (wc + ni * 16 + lr) * 32 + lc * 8);
#pragma unroll
    for (int mi = 0; mi < 4; mi++)
#pragma unroll
      for (int ni = 0; ni < 4; ni++)
        acc[mi][ni] = mfma16(af[mi], bf[ni], acc[mi][ni]);
    __syncthreads();
  }
#pragma unroll
  for (int mi = 0; mi < 4; mi++) {
#pragma unroll
    for (int ni = 0; ni < 4; ni++) {
      int row = bm * 128 + wr + mi * 16 + lc * 4;
      int col = bn * 128 + wc + ni * 16 + lr;
#pragma unroll
      for (int r = 0; r < 4; r++)
        store_out(C, (size_t)(row + r) * N + col, acc[mi][ni][r]);
    }
  }
}

// ---------------- flash attention (causal GQA) ----------------
// 256 threads = 4 waves; wave w owns 16 q-rows (q0w = qc*64 + w*16).
// Block bx processes q-chunk pair (bx, 31-bx) sequentially -> uniform 33 tiles/block.
// Swapped QK^T (mfma(K,Q)): lane holds S row q = q0w+lr, k = kv0+kj*16+lc*4+r.
// In-register softmax; P packed to bf16 in-lane; V pre-permuted (Vf) so PV needs
// no cross-lane traffic. K staged in LDS (KVBLK=64, dbuf, XOR-swizzled).
__global__ __launch_bounds__(256, 2) void attn_k(const ushort_t* __restrict__ Qb,
                                                 const ushort_t* __restrict__ Kb,
                                                 const ushort_t* __restrict__ Vf,
                                                 ushort_t* __restrict__ Yb) {
  __shared__ __attribute__((aligned(16))) ushort_t Ks[2][64 * 128];  // 32 KB
  const int tid = threadIdx.x;
  const int lane = tid & 63;
  const int w = tid >> 6;
  const int lr = lane & 15, lc = lane >> 4;
  const int h = blockIdx.y;
  const int b = blockIdx.z;
  const int kh = h >> 2;
  const int bx = blockIdx.x;

  const ushort_t* Qp = Qb + (size_t)(b * 16 + h) * T_ * D_;
  const ushort_t* Kp = Kb + (size_t)(b * 4 + kh) * T_ * D_;
  const ushort_t* Vfb = Vf + (size_t)(b * 4 + kh) * 262144;

  const int st_row = tid >> 4;   // 0..15, +i*16
  const int st_slot = tid & 15;

#pragma unroll 1
  for (int pass = 0; pass < 2; pass++) {
    const int qc = pass ? (31 - bx) : bx;   // 64-row q-chunk
    const int q0w = qc * 64 + w * 16;
    const int q = q0w + lr;                 // this lane's q-row

    short8 qf[4];
#pragma unroll
    for (int c = 0; c < 4; c++)
      qf[c] = *(const short8*)(Qp + (size_t)(q0w + lr) * D_ + c * 32 + lc * 8);

    f32x4 o[8];
#pragma unroll
    for (int n = 0; n < 8; n++) o[n] = (f32x4)(0.0f);
    float m = -1e30f, l = 0.0f;

    const int nt = qc + 1;

    __syncthreads();  // previous pass done with Ks
#pragma unroll
    for (int i = 0; i < 4; i++) {
      int row = i * 16 + st_row;
      async16(Kp + (size_t)row * D_ + ((st_slot ^ (row & 7)) * 8),
              &Ks[0][0] + row * 128 + st_slot * 8);
    }

#pragma unroll 1
    for (int ti = 0; ti < nt; ti++) {
      __syncthreads();  // K[ti] resident (vmcnt drained); buffers safe
      const int kv0 = ti * 64;
      if (ti + 1 < nt) {
        const ushort_t* Kn = Kp + (size_t)(kv0 + 64) * D_;
        ushort_t* dst = &Ks[(ti + 1) & 1][0];
#pragma unroll
        for (int i = 0; i < 4; i++) {
          int row = i * 16 + st_row;
          async16(Kn + (size_t)row * D_ + ((st_slot ^ (row & 7)) * 8),
                  dst + row * 128 + st_slot * 8);
        }
      }
      const ushort_t* Kl = &Ks[ti & 1][0];
      // V half 0 — early issue, hidden under QK
      const ushort_t* Vt0 = Vfb + (size_t)(ti * 2) * 4096;
      short8 vr0[8];
#pragma unroll
      for (int n = 0; n < 8; n++)
        vr0[n] = *(const short8*)(Vt0 + n * 512 + lane * 8);
      // QK^T swapped: s[kj] lane layout: q = q0w+lr (col), k = kv0+kj*16+lc*4+r (row)
      f32x4 s[4];
#pragma unroll
      for (int kj = 0; kj < 4; kj++) s[kj] = (f32x4)(0.0f);
      __builtin_amdgcn_s_setprio(1);
#pragma unroll
      for (int c = 0; c < 4; c++) {
        short8 kf[4];
#pragma unroll
        for (int kj = 0; kj < 4; kj++)
          kf[kj] = *(const short8*)(Kl + (kj * 16 + lr) * 128 + (((c * 4 + lc) ^ (lr & 7)) * 8));
#pragma unroll
        for (int kj = 0; kj < 4; kj++)
          s[kj] = mfma16(kf[kj], qf[c], s[kj]);
      }
      __builtin_amdgcn_s_setprio(0);
      // V half 1 — hidden under softmax
      const ushort_t* Vt1 = Vfb + (size_t)(ti * 2 + 1) * 4096;
      short8 vr1[8];
#pragma unroll
      for (int n = 0; n < 8; n++)
        vr1[n] = *(const short8*)(Vt1 + n * 512 + lane * 8);
      // in-register softmax (per-lane row q)
      const bool maskt = (kv0 + 63 > q0w);
      float pv[16];
      float mx = -1e30f;
#pragma unroll
      for (int kj = 0; kj < 4; kj++)
#pragma unroll
        for (int r = 0; r < 4; r++) {
          float a = s[kj][r] * RSQRT_D;
          if (maskt && (kv0 + kj * 16 + lc * 4 + r > q)) a = -1e30f;
          pv[kj * 4 + r] = a;
          mx = fmaxf(mx, a);
        }
      mx = fmaxf(mx, __shfl_xor(mx, 16));
      mx = fmaxf(mx, __shfl_xor(mx, 32));
      const bool grow = __any(mx > m);
      const float mn = fmaxf(m, mx);
      float rs = 0.0f;
#pragma unroll
      for (int i = 0; i < 16; i++) {
        pv[i] = exp2f((pv[i] - mn) * L2E);
        rs += pv[i];
      }
      rs += __shfl_xor(rs, 16);
      rs += __shfl_xor(rs, 32);
      // pack P to bf16 A-frags (in-lane; layout matches Vf's sigma)
      unsigned Wd[8];
#pragma unroll
      for (int kj = 0; kj < 4; kj++) {
        Wd[kj * 2] = cvtpk(pv[kj * 4], pv[kj * 4 + 1]);
        Wd[kj * 2 + 1] = cvtpk(pv[kj * 4 + 2], pv[kj * 4 + 3]);
      }
      union { unsigned u[4]; short8 v; } pa0, pa1;
#pragma unroll
      for (int t = 0; t < 4; t++) { pa0.u[t] = Wd[t]; pa1.u[t] = Wd[4 + t]; }
      if (grow) {
        float al = exp2f((m - mn) * L2E);
        m = mn;
        l = l * al + rs;
        float alT[4];
#pragma unroll
        for (int r = 0; r < 4; r++)
          alT[r] = __shfl(al, (lane & 48) | (lc * 4 + r));
#pragma unroll
        for (int n = 0; n < 8; n++)
#pragma unroll
          for (int r = 0; r < 4; r++) o[n][r] *= alT[r];
      } else {
        l += rs;
      }
      __builtin_amdgcn_s_setprio(1);
#pragma unroll
      for (int n = 0; n < 8; n++) o[n] = mfma16(pa0.v, vr0[n], o[n]);
#pragma unroll
      for (int n = 0; n < 8; n++) o[n] = mfma16(pa1.v, vr1[n], o[n]);
      __builtin_amdgcn_s_setprio(0);
    }
    // epilogue: o rows are q = q0w + lc*4 + r; l lives at lane q = q0w + lr
    float inv = 1.0f / l;
    float invT[4];
#pragma unroll
    for (int r = 0; r < 4; r++)
      invT[r] = __shfl(inv, (lane & 48) | (lc * 4 + r));
#pragma unroll
    for (int n = 0; n < 8; n++)
#pragma unroll
      for (int r = 0; r < 4; r++) {
        int qo = q0w + lc * 4 + r;
        int d = n * 16 + lr;
        Yb[(size_t)(b * T_ + qo) * 2048 + h * 128 + d] = f2b(o[n][r] * invT[r]);
      }
  }
}

// ---------------- launch ----------------

extern "C" void kernel_launch(void* const* d_in, const int* in_sizes, int n_in,
                              void* d_out, int out_size, void* d_ws, size_t ws_size,
                              hipStream_t stream) {
  (void)in_sizes; (void)n_in; (void)out_size; (void)ws_size;
  const float* x = (const float*)d_in[0];
  const float* wq = (const float*)d_in[1];
  const float* wkv = (const float*)d_in[2];
  const float* wproj = (const float*)d_in[3];
  const float* omega = (const float*)d_in[4];
  float* out = (float*)d_out;
  char* ws = (char*)d_ws;

  ushort_t* xb     = (ushort_t*)(ws + 0);          // 4096x2048 bf16 = 16.8MB
  ushort_t* wqT    = (ushort_t*)(ws + 16777216);   // 2048x2048 bf16
  ushort_t* wkvT   = (ushort_t*)(ws + 25165824);   // 1024x2048 bf16
  ushort_t* wprojT = (ushort_t*)(ws + 29360128);   // 2048x2048 bf16
  ushort_t* Qraw   = (ushort_t*)(ws + 37748736);   // 4096x2048 bf16
  ushort_t* KVraw  = (ushort_t*)(ws + 54525952);   // 4096x1024 bf16
  ushort_t* Qb     = (ushort_t*)(ws + 62914560);   // [b][h][t][d] bf16
  ushort_t* Kb     = (ushort_t*)(ws + 79691776);   // [b][kh][t][d] bf16
  ushort_t* Vf     = (ushort_t*)(ws + 83886080);   // V fragment-packed, 4MB
  ushort_t* Yb     = (ushort_t*)(ws + 88080384);   // 4096x2048 bf16
  float2*   tab    = (float2*)(ws + 104857600);    // 2048x64 float2 = 1MB

  convert_f32_bf16<<<8192, 256, 0, stream>>>(x, xb, 2097152);
  transpose_to_bf16<<<dim3(64, 64), dim3(32, 8), 0, stream>>>(wq, wqT, 2048, 2048);
  transpose_to_bf16<<<dim3(32, 64), dim3(32, 8), 0, stream>>>(wkv, wkvT, 2048, 1024);
  transpose_to_bf16<<<dim3(64, 64), dim3(32, 8), 0, stream>>>(wproj, wprojT, 2048, 2048);
  rope_tab_k<<<512, 256, 0, stream>>>(omega, tab);

  gemm_bt<<<dim3(16, 32), 256, 0, stream>>>(xb, wqT, Qraw, 4096, 2048, 2048);
  gemm_bt<<<dim3(8, 32), 256, 0, stream>>>(xb, wkvT, KVraw, 4096, 1024, 2048);

  rope_q_k<<<16384, 256, 0, stream>>>(Qraw, tab, Qb);
  rope_k_k<<<4096, 256, 0, stream>>>(KVraw, tab, Kb);
  v_frag_k<<<1024, 256, 0, stream>>>(KVraw, Vf);

  attn_k<<<dim3(16, 16, 2), 256, 0, stream>>>(Qb, Kb, Vf, Yb);

  gemm_bt<<<dim3(16, 32), 256, 0, stream>>>(Yb, wprojT, out, 4096, 2048, 2048);
}

// Round 5
// 222.644 us; speedup vs baseline: 2.5714x; 1.2313x over previous
//
#include <hip/hip_runtime.h>
#include <hip/hip_bf16.h>

#define B_ 2
#define T_ 2048
#define C_ 2048
#define H_ 16
#define KH_ 4
#define D_ 128

typedef unsigned short ushort_t;
typedef __attribute__((ext_vector_type(8))) short short8;
typedef __attribute__((ext_vector_type(4))) float f32x4;

#define RSQRT_D 0.08838834764831845f
#define L2E 1.4426950408889634f

__device__ __forceinline__ ushort_t f2b(float f) {
  union { float f; unsigned u; } v; v.f = f;
  unsigned r = v.u + 0x7fffu + ((v.u >> 16) & 1u);
  return (ushort_t)(r >> 16);
}
__device__ __forceinline__ float b2f(ushort_t u) {
  union { unsigned u; float f; } v; v.u = ((unsigned)u) << 16;
  return v.f;
}

__device__ __forceinline__ f32x4 mfma16(short8 a, short8 b, f32x4 c) {
  return __builtin_amdgcn_mfma_f32_16x16x32_bf16(a, b, c, 0, 0, 0);
}

__device__ __forceinline__ void async16(const void* g, void* l) {
  __builtin_amdgcn_global_load_lds(
      (const __attribute__((address_space(1))) void*)g,
      (__attribute__((address_space(3))) void*)l, 16, 0, 0);
}

// packed f32x2 -> bf16x2 (RTNE); dst.lo = bf16(lo), dst.hi = bf16(hi)
__device__ __forceinline__ unsigned cvtpk(float lo, float hi) {
  unsigned r;
  asm volatile("v_cvt_pk_bf16_f32 %0, %1, %2" : "=v"(r) : "v"(lo), "v"(hi));
  return r;
}

// ---------------- small prep kernels ----------------

__global__ void convert_f32_bf16(const float* __restrict__ in, ushort_t* __restrict__ out, int n4) {
  int i = blockIdx.x * blockDim.x + threadIdx.x;
  if (i >= n4) return;
  float4 v = ((const float4*)in)[i];
  ushort4 o;
  o.x = f2b(v.x); o.y = f2b(v.y); o.z = f2b(v.z); o.w = f2b(v.w);
  ((ushort4*)out)[i] = o;
}

// out[c][r] = bf16(in[r][c]);  in: R x C f32, out: C x R bf16
__global__ void transpose_to_bf16(const float* __restrict__ in, ushort_t* __restrict__ out, int R, int C) {
  __shared__ float tile[32][33];
  int c0 = blockIdx.x * 32, r0 = blockIdx.y * 32;
  int tx = threadIdx.x, ty = threadIdx.y;
#pragma unroll
  for (int i = 0; i < 4; i++) {
    int r = ty + i * 8;
    tile[r][tx] = in[(size_t)(r0 + r) * C + c0 + tx];
  }
  __syncthreads();
#pragma unroll
  for (int i = 0; i < 4; i++) {
    int r = ty + i * 8;
    out[(size_t)(c0 + r) * R + r0 + tx] = f2b(tile[tx][r]);
  }
}

// cos/sin table: tab[t*64+d] = (cos(t*omega[d]), sin(t*omega[d]))
__global__ void rope_tab_k(const float* __restrict__ omega, float2* __restrict__ tab) {
  int idx = blockIdx.x * blockDim.x + threadIdx.x;  // 2048*64
  int d = idx & 63;
  int t = idx >> 6;
  float ang = (float)t * omega[d];
  tab[idx] = make_float2(cosf(ang), sinf(ang));
}

// QKVraw [b*T+t][3072]: cols 0..2047 = q -> rope (pre-scaled by 1/sqrt(D)) -> Qb [(b*16+h)*T + t][d]
__global__ void rope_q_k(const ushort_t* __restrict__ QKVraw, const float2* __restrict__ tab,
                         ushort_t* __restrict__ Qb) {
  int idx = blockIdx.x * blockDim.x + threadIdx.x;  // B*T*H*64 = 4194304
  int d = idx & 63;
  int h = (idx >> 6) & 15;
  int t = (idx >> 10) & 2047;
  int b = idx >> 21;
  size_t in_off = (size_t)(b * 2048 + t) * 3072 + h * 128 + d;
  float x1 = b2f(QKVraw[in_off]);
  float x2 = b2f(QKVraw[in_off + 64]);
  float2 cs = tab[t * 64 + d];
  size_t out_off = ((size_t)(b * 16 + h) * 2048 + t) * 128 + d;
  Qb[out_off] = f2b((x1 * cs.x - x2 * cs.y) * RSQRT_D);
  Qb[out_off + 64] = f2b((x1 * cs.y + x2 * cs.x) * RSQRT_D);
}

// QKVraw cols 2048..2559 = k -> rope -> Kb [(b*4+kh)*T + t][d]
__global__ void rope_k_k(const ushort_t* __restrict__ QKVraw, const float2* __restrict__ tab,
                         ushort_t* __restrict__ Kb) {
  int idx = blockIdx.x * blockDim.x + threadIdx.x;  // B*T*KH*64 = 1048576
  int d = idx & 63;
  int kh = (idx >> 6) & 3;
  int t = (idx >> 8) & 2047;
  int b = idx >> 19;
  size_t in_off = (size_t)(b * 2048 + t) * 3072 + 2048 + kh * 128 + d;
  float x1 = b2f(QKVraw[in_off]);
  float x2 = b2f(QKVraw[in_off + 64]);
  float2 cs = tab[t * 64 + d];
  size_t out_off = ((size_t)(b * 4 + kh) * 2048 + t) * 128 + d;
  Kb[out_off] = f2b(x1 * cs.x - x2 * cs.y);
  Kb[out_off + 64] = f2b(x1 * cs.y + x2 * cs.x);
}

// V fragment pre-pack: Vf short8 index = (((z*32+tile)*2+hv)*8+n)*64 + lane
// element j = V[b][t = tile*64 + kl][kh][d = n*16 + (lane&15)]
// kl = (hv*2 + ((j>>1)>>1))*16 + (lane>>4)*4 + 2*((j>>1)&1) + (j&1)
__global__ void v_frag_k(const ushort_t* __restrict__ QKVraw, ushort_t* __restrict__ Vf) {
  int idx = blockIdx.x * blockDim.x + threadIdx.x;  // 262144 short8 units
  int lane = idx & 63;
  int n = (idx >> 6) & 7;
  int hv = (idx >> 9) & 1;
  int tile = (idx >> 10) & 31;
  int z = idx >> 15;  // b*4+kh
  int b = z >> 2, kh = z & 3;
  int lr = lane & 15, lc = lane >> 4;
  int d = n * 16 + lr;
  union { ushort_t u[8]; short8 v; } out;
#pragma unroll
  for (int j = 0; j < 8; j++) {
    int tw = j >> 1, par = j & 1;
    int kl = (hv * 2 + (tw >> 1)) * 16 + lc * 4 + 2 * (tw & 1) + par;
    int t = tile * 64 + kl;
    out.u[j] = QKVraw[(size_t)(b * 2048 + t) * 3072 + 2560 + kh * 128 + d];
  }
  *(short8*)(Vf + (size_t)idx * 8) = out.v;
}

// ---------------- GEMM: C[M][N] = A[M][K] @ Bt[N][K]^T  (bf16 in, f32 acc) ----------------
// T3-minimum 2-phase: double-buffered LDS, stage(t+1) issued before compute(t),
// one barrier per K-step (barrier's vmcnt-drain completes the prefetch).

__device__ __forceinline__ void store_out(float* C, size_t idx, float v) { C[idx] = v; }
__device__ __forceinline__ void store_out(ushort_t* C, size_t idx, float v) { C[idx] = f2b(v); }

template <typename OUT_T>
__global__ __launch_bounds__(256) void gemm_bt(const ushort_t* __restrict__ A,
                                               const ushort_t* __restrict__ Bt,
                                               OUT_T* __restrict__ C,
                                               int M, int N, int K) {
  __shared__ __attribute__((aligned(16))) ushort_t As[2][128 * 32];
  __shared__ __attribute__((aligned(16))) ushort_t Bs[2][128 * 32];
  const int tid = threadIdx.x;
  const int lane = tid & 63;
  const int w = tid >> 6;
  const int bm = blockIdx.y, bn = blockIdx.x;
  const int lr = lane & 15, lc = lane >> 4;
  const int wr = (w >> 1) * 64, wc = (w & 1) * 64;
  const ushort_t* Ab = A + (size_t)bm * 128 * K;
  const ushort_t* Bb = Bt + (size_t)bn * 128 * K;
  const int srow = tid >> 2;
  const int scol = (tid & 3) * 8;
  f32x4 acc[4][4];
#pragma unroll
  for (int i = 0; i < 4; i++)
#pragma unroll
    for (int j = 0; j < 4; j++) acc[i][j] = (f32x4)(0.0f);

  // prologue: stage tile 0
  {
    async16(Ab + (size_t)srow * K + scol, &As[0][0] + srow * 32 + scol);
    async16(Ab + (size_t)(srow + 64) * K + scol, &As[0][0] + (srow + 64) * 32 + scol);
    async16(Bb + (size_t)srow * K + scol, &Bs[0][0] + srow * 32 + scol);
    async16(Bb + (size_t)(srow + 64) * K + scol, &Bs[0][0] + (srow + 64) * 32 + scol);
  }
  __syncthreads();

  const int nt = K >> 5;
#pragma unroll 2
  for (int t = 0; t < nt; t++) {
    const int cur = t & 1;
    if (t + 1 < nt) {
      const int k1 = (t + 1) << 5;
      ushort_t* Ad = &As[cur ^ 1][0];
      ushort_t* Bd = &Bs[cur ^ 1][0];
      async16(Ab + (size_t)srow * K + k1 + scol, Ad + srow * 32 + scol);
      async16(Ab + (size_t)(srow + 64) * K + k1 + scol, Ad + (srow + 64) * 32 + scol);
      async16(Bb + (size_t)srow * K + k1 + scol, Bd + srow * 32 + scol);
      async16(Bb + (size_t)(srow + 64) * K + k1 + scol, Bd + (srow + 64) * 32 + scol);
    }
    const ushort_t* Al = &As[cur][0];
    const ushort_t* Bl = &Bs[cur][0];
    short8 af[4], bf[4];
#pragma unroll
    for (int mi = 0; mi < 4; mi++)
      af[mi] = *(const short8*)(Al + (wr + mi * 16 + lr) * 32 + lc * 8);
#pragma unroll
    for (int ni = 0; ni < 4; ni++)
      bf[ni] = *(const short8*)(Bl + (wc + ni * 16 + lr) * 32 + lc * 8);
#pragma unroll
    for (int mi = 0; mi < 4; mi++)
#pragma unroll
      for (int ni = 0; ni < 4; ni++)
        acc[mi][ni] = mfma16(af[mi], bf[ni], acc[mi][ni]);
    __syncthreads();  // drains vmcnt (prefetch t+1 landed); all waves done with buf[cur]
  }
#pragma unroll
  for (int mi = 0; mi < 4; mi++) {
#pragma unroll
    for (int ni = 0; ni < 4; ni++) {
      int row = bm * 128 + wr + mi * 16 + lc * 4;
      int col = bn * 128 + wc + ni * 16 + lr;
#pragma unroll
      for (int r = 0; r < 4; r++)
        store_out(C, (size_t)(row + r) * N + col, acc[mi][ni][r]);
    }
  }
}

// ---------------- flash attention (causal GQA) ----------------
// 256 threads = 4 waves; wave w owns 16 q-rows (q0w = qc*64 + w*16).
// Block bx processes q-chunk pair (bx, 31-bx) sequentially -> uniform 33 tiles/block.
// Swapped QK^T (mfma(K,Q)): lane holds S row q = q0w+lr, k = kv0+kj*16+lc*4+r.
// Q pre-scaled by 1/sqrt(D). In-register softmax + defer-max (thr 5.5 => P<=2^8).
// K staged in LDS (KVBLK=64, dbuf, ADDITIVE swizzle chunk=(X+row)&15 -> 4-way max).
__global__ __launch_bounds__(256, 2) void attn_k(const ushort_t* __restrict__ Qb,
                                                 const ushort_t* __restrict__ Kb,
                                                 const ushort_t* __restrict__ Vf,
                                                 ushort_t* __restrict__ Yb) {
  __shared__ __attribute__((aligned(16))) ushort_t Ks[2][64 * 128];  // 32 KB
  const int tid = threadIdx.x;
  const int lane = tid & 63;
  const int w = tid >> 6;
  const int lr = lane & 15, lc = lane >> 4;
  const int h = blockIdx.y;
  const int b = blockIdx.z;
  const int kh = h >> 2;
  const int bx = blockIdx.x;

  const ushort_t* Qp = Qb + (size_t)(b * 16 + h) * T_ * D_;
  const ushort_t* Kp = Kb + (size_t)(b * 4 + kh) * T_ * D_;
  const ushort_t* Vfb = Vf + (size_t)(b * 4 + kh) * 262144;

  const int st_row = tid >> 4;   // 0..15, +i*16
  const int st_slot = tid & 15;

#pragma unroll 1
  for (int pass = 0; pass < 2; pass++) {
    const int qc = pass ? (31 - bx) : bx;   // 64-row q-chunk
    const int q0w = qc * 64 + w * 16;
    const int q = q0w + lr;                 // this lane's q-row

    short8 qf[4];
#pragma unroll
    for (int c = 0; c < 4; c++)
      qf[c] = *(const short8*)(Qp + (size_t)(q0w + lr) * D_ + c * 32 + lc * 8);

    f32x4 o[8];
#pragma unroll
    for (int n = 0; n < 8; n++) o[n] = (f32x4)(0.0f);
    float m = -1e30f, l = 0.0f;

    const int nt = qc + 1;

    __syncthreads();  // previous pass done with Ks
#pragma unroll
    for (int i = 0; i < 4; i++) {
      int row = i * 16 + st_row;
      async16(Kp + (size_t)row * D_ + (((st_slot - row) & 15) * 8),
              &Ks[0][0] + row * 128 + st_slot * 8);
    }

#pragma unroll 1
    for (int ti = 0; ti < nt; ti++) {
      __syncthreads();  // K[ti] resident (vmcnt drained); buffers safe
      const int kv0 = ti * 64;
      if (ti + 1 < nt) {
        const ushort_t* Kn = Kp + (size_t)(kv0 + 64) * D_;
        ushort_t* dst = &Ks[(ti + 1) & 1][0];
#pragma unroll
        for (int i = 0; i < 4; i++) {
          int row = i * 16 + st_row;
          async16(Kn + (size_t)row * D_ + (((st_slot - row) & 15) * 8),
                  dst + row * 128 + st_slot * 8);
        }
      }
      const ushort_t* Kl = &Ks[ti & 1][0];
      // V half 0 — early issue, hidden under QK
      const ushort_t* Vt0 = Vfb + (size_t)(ti * 2) * 4096;
      short8 vr0[8];
#pragma unroll
      for (int n = 0; n < 8; n++)
        vr0[n] = *(const short8*)(Vt0 + n * 512 + lane * 8);
      // QK^T swapped: s[kj] lane layout: q = q0w+lr (col), k = kv0+kj*16+lc*4+r (row)
      f32x4 s[4];
#pragma unroll
      for (int kj = 0; kj < 4; kj++) s[kj] = (f32x4)(0.0f);
      __builtin_amdgcn_s_setprio(1);
#pragma unroll
      for (int c = 0; c < 4; c++) {
        short8 kf[4];
#pragma unroll
        for (int kj = 0; kj < 4; kj++)
          kf[kj] = *(const short8*)(Kl + (kj * 16 + lr) * 128 + (((c * 4 + lc + lr) & 15) * 8));
#pragma unroll
        for (int kj = 0; kj < 4; kj++)
          s[kj] = mfma16(kf[kj], qf[c], s[kj]);
      }
      __builtin_amdgcn_s_setprio(0);
      // V half 1 — hidden under softmax
      const ushort_t* Vt1 = Vfb + (size_t)(ti * 2 + 1) * 4096;
      short8 vr1[8];
#pragma unroll
      for (int n = 0; n < 8; n++)
        vr1[n] = *(const short8*)(Vt1 + n * 512 + lane * 8);
      // in-register softmax (per-lane row q); mask VALU only on diagonal tile
      float pv[16];
      float mx = -1e30f;
      if (kv0 + 63 > q0w) {
#pragma unroll
        for (int kj = 0; kj < 4; kj++)
#pragma unroll
          for (int r = 0; r < 4; r++) {
            float a = s[kj][r];
            if (kv0 + kj * 16 + lc * 4 + r > q) a = -1e30f;
            pv[kj * 4 + r] = a;
            mx = fmaxf(mx, a);
          }
      } else {
#pragma unroll
        for (int kj = 0; kj < 4; kj++)
#pragma unroll
          for (int r = 0; r < 4; r++) {
            float a = s[kj][r];
            pv[kj * 4 + r] = a;
            mx = fmaxf(mx, a);
          }
      }
      mx = fmaxf(mx, __shfl_xor(mx, 16));
      mx = fmaxf(mx, __shfl_xor(mx, 32));
      // defer-max: only rescale when some row grew > 5.5 (ln units => P <= 2^8)
      const bool need = __any(mx > m + 5.5f);
      const float mn = need ? fmaxf(m, mx) : m;
      float rs = 0.0f;
#pragma unroll
      for (int i = 0; i < 16; i++) {
        pv[i] = exp2f((pv[i] - mn) * L2E);
        rs += pv[i];
      }
      rs += __shfl_xor(rs, 16);
      rs += __shfl_xor(rs, 32);
      // pack P to bf16 A-frags (in-lane; layout matches Vf's sigma)
      unsigned Wd[8];
#pragma unroll
      for (int kj = 0; kj < 4; kj++) {
        Wd[kj * 2] = cvtpk(pv[kj * 4], pv[kj * 4 + 1]);
        Wd[kj * 2 + 1] = cvtpk(pv[kj * 4 + 2], pv[kj * 4 + 3]);
      }
      union { unsigned u[4]; short8 v; } pa0, pa1;
#pragma unroll
      for (int t = 0; t < 4; t++) { pa0.u[t] = Wd[t]; pa1.u[t] = Wd[4 + t]; }
      if (need) {
        float al = exp2f((m - mn) * L2E);
        m = mn;
        l = l * al + rs;
        float alT[4];
#pragma unroll
        for (int r = 0; r < 4; r++)
          alT[r] = __shfl(al, (lane & 48) | (lc * 4 + r));
#pragma unroll
        for (int n = 0; n < 8; n++)
#pragma unroll
          for (int r = 0; r < 4; r++) o[n][r] *= alT[r];
      } else {
        l += rs;
      }
      __builtin_amdgcn_s_setprio(1);
#pragma unroll
      for (int n = 0; n < 8; n++) o[n] = mfma16(pa0.v, vr0[n], o[n]);
#pragma unroll
      for (int n = 0; n < 8; n++) o[n] = mfma16(pa1.v, vr1[n], o[n]);
      __builtin_amdgcn_s_setprio(0);
    }
    // epilogue: o rows are q = q0w + lc*4 + r; l lives at lane q = q0w + lr
    float inv = 1.0f / l;
    float invT[4];
#pragma unroll
    for (int r = 0; r < 4; r++)
      invT[r] = __shfl(inv, (lane & 48) | (lc * 4 + r));
#pragma unroll
    for (int n = 0; n < 8; n++)
#pragma unroll
      for (int r = 0; r < 4; r++) {
        int qo = q0w + lc * 4 + r;
        int d = n * 16 + lr;
        Yb[(size_t)(b * T_ + qo) * 2048 + h * 128 + d] = f2b(o[n][r] * invT[r]);
      }
  }
}

// ---------------- launch ----------------

extern "C" void kernel_launch(void* const* d_in, const int* in_sizes, int n_in,
                              void* d_out, int out_size, void* d_ws, size_t ws_size,
                              hipStream_t stream) {
  (void)in_sizes; (void)n_in; (void)out_size; (void)ws_size;
  const float* x = (const float*)d_in[0];
  const float* wq = (const float*)d_in[1];
  const float* wkv = (const float*)d_in[2];
  const float* wproj = (const float*)d_in[3];
  const float* omega = (const float*)d_in[4];
  float* out = (float*)d_out;
  char* ws = (char*)d_ws;

  ushort_t* xb     = (ushort_t*)(ws + 0);          // 4096x2048 bf16 = 16.8MB
  ushort_t* wqkvT  = (ushort_t*)(ws + 16777216);   // [3072][2048] bf16 (wqT then wkvT)
  ushort_t* wkvT   = (ushort_t*)(ws + 25165824);   // tail of wqkvT
  ushort_t* wprojT = (ushort_t*)(ws + 29360128);   // 2048x2048 bf16
  ushort_t* QKVraw = (ushort_t*)(ws + 37748736);   // 4096x3072 bf16 = 25.2MB
  ushort_t* Qb     = (ushort_t*)(ws + 62914560);   // [b][h][t][d] bf16
  ushort_t* Kb     = (ushort_t*)(ws + 79691776);   // [b][kh][t][d] bf16
  ushort_t* Vf     = (ushort_t*)(ws + 83886080);   // V fragment-packed, 4MB
  ushort_t* Yb     = (ushort_t*)(ws + 88080384);   // 4096x2048 bf16
  float2*   tab    = (float2*)(ws + 104857600);    // 2048x64 float2 = 1MB

  convert_f32_bf16<<<8192, 256, 0, stream>>>(x, xb, 2097152);
  transpose_to_bf16<<<dim3(64, 64), dim3(32, 8), 0, stream>>>(wq, wqkvT, 2048, 2048);
  transpose_to_bf16<<<dim3(32, 64), dim3(32, 8), 0, stream>>>(wkv, wkvT, 2048, 1024);
  transpose_to_bf16<<<dim3(64, 64), dim3(32, 8), 0, stream>>>(wproj, wprojT, 2048, 2048);
  rope_tab_k<<<512, 256, 0, stream>>>(omega, tab);

  // merged QKV projection: [4096,2048] @ [3072,2048]^T -> [4096,3072]
  gemm_bt<<<dim3(24, 32), 256, 0, stream>>>(xb, wqkvT, QKVraw, 4096, 3072, 2048);

  rope_q_k<<<16384, 256, 0, stream>>>(QKVraw, tab, Qb);
  rope_k_k<<<4096, 256, 0, stream>>>(QKVraw, tab, Kb);
  v_frag_k<<<1024, 256, 0, stream>>>(QKVraw, Vf);

  attn_k<<<dim3(16, 16, 2), 256, 0, stream>>>(Qb, Kb, Vf, Yb);

  gemm_bt<<<dim3(16, 32), 256, 0, stream>>>(Yb, wprojT, out, 4096, 2048, 2048);
}